// Round 5
// baseline (3758.145 us; speedup 1.0000x reference)
//
#include <hip/hip_runtime.h>
#include <hip/hip_cooperative_groups.h>
#include <cstdint>
#include <cstddef>

namespace cg = cooperative_groups;

typedef __bf16 bf16;
typedef float f32x4 __attribute__((ext_vector_type(4)));
typedef bf16  bf16x8 __attribute__((ext_vector_type(8)));

#define NEGV (-1e30f)

// B=64, N=256, IN=1024, HID=OUT=2048
enum { EPI_STORE = 0, EPI_ADD = 1, EPI_BIAS_RELU = 2, EPI_BIAS = 3,
       EPI_STORE_T = 5, EPI_BIAS_RELU_SCALE_T = 6, EPI_PART = 7, EPI_PARTP = 8 };

__device__ __forceinline__ void gload16(const void* g, void* l) {
    __builtin_amdgcn_global_load_lds((const __attribute__((address_space(1))) void*)g,
                                     (__attribute__((address_space(3))) void*)l, 16, 0, 0);
}

// Bijective XCD-aware block swizzle (m204): contiguous tile chunk per XCD.
__device__ __forceinline__ void xcd_swz(int& bx, int& by, int& bz) {
    const int gx = (int)gridDim.x, gy = (int)gridDim.y, gz = (int)gridDim.z;
    const int nwg = gx * gy * gz;
    const int lid = (bz * gy + by) * gx + bx;
    const int q = nwg >> 3, r = nwg & 7;
    const int xcd = lid & 7, idx = lid >> 3;
    int swz = (xcd < r ? xcd * (q + 1) : r * (q + 1) + (xcd - r) * q) + idx;
    bx = swz % gx; swz /= gx;
    by = swz % gy; bz = swz / gy;
}

// bf16 MFMA GEMM (m97 structure): C[bz] = epi(A[bz] @ B[bz]^T-layout)
// A: [M][K] bf16 row-major.  B: NT layout [N][K] bf16 row-major.
// Tile: 128 x (NTJ*32).  NTJ=4 -> 128x128; NTJ=2 -> 128x64 (4 waves).
// z-batching: ptr += bz * s{A,B,C}.
// EPI_PART: 8 K-slices over two partial-sum A buffers (halves at stride sH):
//   bz = batch*8 + ks; h = ks>>2 selects A-half, kk = ks&3 selects K/4 range;
//   output slice C + (ks*nbatch + batch)*sC  (nbatch = gridDim.z/8).
// EPI_PARTP: split-K=2 producer; bz selects K-half; C += bz*sC (partial sums).
template<int EPI, typename CT, int NTJ>
__global__ __launch_bounds__(256, 2)
void hgemm_k(const bf16* __restrict__ Ab, const bf16* __restrict__ Bb,
             CT* __restrict__ Cb, const int M, const int N, const int K,
             const long long sA, const long long sB, const long long sC,
             const long long sH, const float* __restrict__ bias)
{
    __shared__ bf16 Asl[128 * 32];
    __shared__ bf16 Bsl[NTJ * 32 * 32];
    int bxs = (int)blockIdx.x, bys = (int)blockIdx.y, bzs = (int)blockIdx.z;
    xcd_swz(bxs, bys, bzs);
    const int bz = bzs;
    int ba = bz, kbeg = 0, klen = K;
    long long aoff = 0;
    if constexpr (EPI == EPI_PART) {
        ba = bz >> 3;
        const int ks = bz & 7;
        kbeg = (ks & 3) * (K >> 2); klen = K >> 2;
        aoff = (long long)(ks >> 2) * sH;
    }
    if constexpr (EPI == EPI_PARTP) {
        ba = 0; kbeg = bz * (K >> 1); klen = K >> 1;
    }
    const bf16* __restrict__ A = Ab + (long long)ba * sA + aoff;
    const bf16* __restrict__ B = Bb + (long long)ba * sB;
    CT* __restrict__ C;
    if constexpr (EPI == EPI_PART)
        C = Cb + (long long)((bz & 7) * ((int)gridDim.z >> 3) + (bz >> 3)) * sC;
    else
        C = Cb + (long long)bz * sC;

    const int m0 = bys * 128, n0 = bxs * (NTJ * 32);
    const int tid = (int)threadIdx.x;
    const int lane = tid & 63, wave = tid >> 6;
    const int wm = (wave & 1) * 64, wn = (wave >> 1) * (NTJ * 16);
    const int lrow = lane & 15, quad = lane >> 4;

    f32x4 acc[4][NTJ];
    const f32x4 zero = {0.f, 0.f, 0.f, 0.f};
#pragma unroll
    for (int i = 0; i < 4; ++i)
#pragma unroll
        for (int j = 0; j < NTJ; ++j) acc[i][j] = zero;

    const int sr = tid >> 2, sck = (tid & 3) * 8;
    const bf16* ga0 = A + (long long)(m0 + sr) * K + kbeg + sck;
    const bf16* ga1 = ga0 + (long long)64 * K;
    const bf16* gb0 = B + (long long)(n0 + sr) * K + kbeg + sck;
    const bf16* gb1 = gb0 + (long long)64 * K;      // NTJ==4 only
    bf16* la0 = Asl + tid * 8;
    bf16* la1 = Asl + 2048 + tid * 8;
    bf16* lb0 = Bsl + tid * 8;
    bf16* lb1 = Bsl + 2048 + tid * 8;               // NTJ==4 only
    const bf16* ar = Asl + (wm + lrow) * 32 + quad * 8;
    const bf16* br = Bsl + (wn + lrow) * 32 + quad * 8;

    for (int k0 = 0; k0 < klen; k0 += 32) {
        gload16(ga0, la0); gload16(ga1, la1);
        gload16(gb0, lb0);
        if constexpr (NTJ == 4) gload16(gb1, lb1);
        ga0 += 32; ga1 += 32; gb0 += 32; gb1 += 32;
        __syncthreads();
        bf16x8 af[4], bfr[NTJ];
#pragma unroll
        for (int t = 0; t < 4; ++t) af[t] = *(const bf16x8*)(ar + t * 512);
#pragma unroll
        for (int t = 0; t < NTJ; ++t) bfr[t] = *(const bf16x8*)(br + t * 512);
#pragma unroll
        for (int i = 0; i < 4; ++i)
#pragma unroll
            for (int j = 0; j < NTJ; ++j)
                acc[i][j] = __builtin_amdgcn_mfma_f32_16x16x32_bf16(af[i], bfr[j], acc[i][j], 0, 0, 0);
        __syncthreads();
    }

    // C/D layout: col = lane&15, row = quad*4 + reg   [m89-verified]
#pragma unroll
    for (int ti = 0; ti < 4; ++ti) {
        const int gm0 = m0 + wm + ti * 16 + quad * 4;
#pragma unroll
        for (int r = 0; r < 4; ++r) {
            const int gm = gm0 + r;
#pragma unroll
            for (int tj = 0; tj < NTJ; ++tj) {
                const int gn = n0 + wn + tj * 16 + lrow;
                const float v = acc[ti][tj][r];
                CT* cp = C + (size_t)gm * N + gn;
                if constexpr (EPI == EPI_STORE)          *cp = (CT)v;
                else if constexpr (EPI == EPI_PART)      *cp = (CT)v;
                else if constexpr (EPI == EPI_PARTP)     *cp = (CT)v;
                else if constexpr (EPI == EPI_ADD)       *cp = (CT)((float)*cp + v);
                else if constexpr (EPI == EPI_BIAS_RELU) *cp = (CT)fmaxf(v + bias[gn], 0.f);
                else if constexpr (EPI == EPI_BIAS)      *cp = (CT)(v + bias[gn]);
            }
        }
    }
}

// Paired-output GEMM: two N=2048 GEMMs sharing the A operand, fused via z.
// z in [0,4): g = z&1 (graph), w = z>>1 (which B/epilogue).
//   w=0: B=B0, epilogue EPI0 (T-type) -> C0 + g*sC0
//   w=1: B=B1, epilogue EPI1 (row-major) -> C1 + g*sC1
// A = Ab + sel*sA, sel = (w==0 && SWAPA0) ? g^1 : g.
// T-epilogue writes per-256-row-batch transposed: C[b][n][m] (b = gm>>8).
template<int EPI0, int EPI1, bool SWAPA0>
__global__ __launch_bounds__(256, 2)
void hgemm2_k(const bf16* __restrict__ Ab,
              const bf16* __restrict__ B0b, const bf16* __restrict__ B1b,
              bf16* __restrict__ C0b, bf16* __restrict__ C1b,
              const int M, const int N, const int K,
              const long long sA, const long long sC0, const long long sC1,
              const long long sR,
              const float* __restrict__ bias0, const float* __restrict__ bias1,
              const float* __restrict__ rowscale)
{
    __shared__ bf16 Asl[128 * 32];
    __shared__ bf16 Bsl[128 * 32];
    int bxs = (int)blockIdx.x, bys = (int)blockIdx.y, bzs = (int)blockIdx.z;
    xcd_swz(bxs, bys, bzs);
    const int bz = bzs;
    const int g = bz & 1, wsel = bz >> 1;
    const int asel = (wsel == 0 && SWAPA0) ? (g ^ 1) : g;
    const bf16* __restrict__ A = Ab + (long long)asel * sA;
    const bf16* __restrict__ B = wsel ? B1b : B0b;
    bf16* __restrict__ C = wsel ? (C1b + (long long)g * sC1)
                                : (C0b + (long long)g * sC0);
    const float* __restrict__ bias = wsel ? bias1 : bias0;
    const float* __restrict__ rs = rowscale + (long long)g * sR;

    const int m0 = bys * 128, n0 = bxs * 128;
    const int tid = (int)threadIdx.x;
    const int lane = tid & 63, wave = tid >> 6;
    const int wm = (wave & 1) * 64, wn = (wave >> 1) * 64;
    const int lrow = lane & 15, quad = lane >> 4;

    f32x4 acc[4][4];
    const f32x4 zero = {0.f, 0.f, 0.f, 0.f};
#pragma unroll
    for (int i = 0; i < 4; ++i)
#pragma unroll
        for (int j = 0; j < 4; ++j) acc[i][j] = zero;

    const int sr = tid >> 2, sck = (tid & 3) * 8;
    const bf16* ga0 = A + (long long)(m0 + sr) * K + sck;
    const bf16* ga1 = ga0 + (long long)64 * K;
    const bf16* gb0 = B + (long long)(n0 + sr) * K + sck;
    const bf16* gb1 = gb0 + (long long)64 * K;
    bf16* la0 = Asl + tid * 8;
    bf16* la1 = Asl + 2048 + tid * 8;
    bf16* lb0 = Bsl + tid * 8;
    bf16* lb1 = Bsl + 2048 + tid * 8;
    const bf16* ar = Asl + (wm + lrow) * 32 + quad * 8;
    const bf16* br = Bsl + (wn + lrow) * 32 + quad * 8;

    for (int k0 = 0; k0 < K; k0 += 32) {
        gload16(ga0, la0); gload16(ga1, la1);
        gload16(gb0, lb0); gload16(gb1, lb1);
        ga0 += 32; ga1 += 32; gb0 += 32; gb1 += 32;
        __syncthreads();
        bf16x8 af[4], bfr[4];
#pragma unroll
        for (int t = 0; t < 4; ++t) {
            af[t]  = *(const bf16x8*)(ar + t * 512);
            bfr[t] = *(const bf16x8*)(br + t * 512);
        }
#pragma unroll
        for (int i = 0; i < 4; ++i)
#pragma unroll
            for (int j = 0; j < 4; ++j)
                acc[i][j] = __builtin_amdgcn_mfma_f32_16x16x32_bf16(af[i], bfr[j], acc[i][j], 0, 0, 0);
        __syncthreads();
    }

    if (wsel == 0) {
        // T-epilogue: per-256-row-batch transposed, packed 4x bf16 along m
#pragma unroll
        for (int ti = 0; ti < 4; ++ti) {
            const int gm0 = m0 + wm + ti * 16 + quad * 4;
#pragma unroll
            for (int tj = 0; tj < 4; ++tj) {
                const int gn = n0 + wn + tj * 16 + lrow;
                union { bf16 h[4]; uint2 u; } p;
#pragma unroll
                for (int r = 0; r < 4; ++r) {
                    float v = acc[ti][tj][r];
                    if constexpr (EPI0 == EPI_BIAS_RELU_SCALE_T)
                        v = fmaxf(v + bias[gn], 0.f) * rs[gm0 + r];
                    p.h[r] = (bf16)v;
                }
                *(uint2*)(C + ((size_t)(gm0 >> 8)) * 524288 +
                          (size_t)gn * 256 + (gm0 & 255)) = p.u;
            }
        }
    } else {
#pragma unroll
        for (int ti = 0; ti < 4; ++ti) {
            const int gm0 = m0 + wm + ti * 16 + quad * 4;
#pragma unroll
            for (int r = 0; r < 4; ++r) {
                const int gm = gm0 + r;
#pragma unroll
                for (int tj = 0; tj < 4; ++tj) {
                    const int gn = n0 + wn + tj * 16 + lrow;
                    const float v = acc[ti][tj][r];
                    bf16* cp = C + (size_t)gm * N + gn;
                    if constexpr (EPI1 == EPI_BIAS_RELU) *cp = (bf16)fmaxf(v + bias[gn], 0.f);
                    else                                 *cp = (bf16)(v + bias[gn]);
                }
            }
        }
    }
}

// fp32 [K][N] -> bf16 [N][K]  (weight transpose-convert)
__global__ __launch_bounds__(256)
void wtrans_k(const float* __restrict__ W, bf16* __restrict__ Wt, const int K, const int N)
{
    __shared__ float tl[32][33];
    const int k0 = blockIdx.y * 32, n0 = blockIdx.x * 32;
    const int tx = (int)threadIdx.x & 31, ty = (int)threadIdx.x >> 5;
#pragma unroll
    for (int q = 0; q < 4; ++q)
        tl[ty + 8 * q][tx] = W[(size_t)(k0 + ty + 8 * q) * N + n0 + tx];
    __syncthreads();
#pragma unroll
    for (int q = 0; q < 4; ++q)
        Wt[(size_t)(n0 + ty + 8 * q) * K + k0 + tx] = (bf16)tl[tx][ty + 8 * q];
}

// fp32 -> bf16 elementwise (vectorized)
__global__ __launch_bounds__(256)
void cvt_k(const float4* __restrict__ in, uint2* __restrict__ out, const long long n4)
{
    long long i = (long long)blockIdx.x * 256 + threadIdx.x;
    const long long st = (long long)gridDim.x * 256;
    for (; i < n4; i += st) {
        const float4 v = in[i];
        union { bf16 h[4]; uint2 u; } p;
        p.h[0] = (bf16)v.x; p.h[1] = (bf16)v.y; p.h[2] = (bf16)v.z; p.h[3] = (bf16)v.w;
        out[i] = p.u;
    }
}

// rcs_cg[((b>>nbl2)*2+g)*nb + (b&(nb-1))][j] = 1 / max(sum_i |A[b,i,j]|, 1e-12)
__global__ __launch_bounds__(256)
void colsum_rcp_k(const float* __restrict__ A, float* __restrict__ rcs,
                  const int nbl2, const int g)
{
    const int b = blockIdx.x, j = (int)threadIdx.x;
    const int cch = b >> nbl2, ii = b & ((1 << nbl2) - 1), nb = 1 << nbl2;
    const float* p = A + (size_t)b * 65536;
    float s = 0.f;
    for (int i = 0; i < 256; ++i) s += fabsf(p[i * 256 + j]);
    rcs[(size_t)((cch * 2 + g) * nb + ii) * 256 + j] = 1.f / fmaxf(s, 1e-12f);
}

// S[t] = mask ? (sum_ks Spart[ks][t]) / tau : NEG     (one chunk: nb batches)
__global__ __launch_bounds__(256)
void mask_tau_red_k(const float* __restrict__ Sp, float* __restrict__ S,
                    const int* __restrict__ n1p, const int* __restrict__ n2p,
                    const int* __restrict__ taup, const int nb)
{
    const size_t t = (size_t)blockIdx.x * 256 + threadIdx.x;
    const int b = (int)(t >> 16), i = (int)((t >> 8) & 255), j = (int)(t & 255);
    const size_t stride = (size_t)nb << 16;
    float s = 0.f;
#pragma unroll
    for (int ks = 0; ks < 8; ++ks) s += Sp[ks * stride + t];
    const float tau = (float)taup[0];
    S[t] = (i < n1p[b] && j < n2p[b]) ? s / tau : NEGV;
}

// online logsumexp partial merge: (m,s) x (m,s) -> (m,s)
__device__ __forceinline__ float2 lse_comb(float2 x, float2 y) {
    const float M = fmaxf(x.x, y.x);
    float2 r; r.x = M; r.y = x.y * expf(x.x - M) + y.y * expf(y.x - M);
    return r;
}

// Cooperative fused Sinkhorn: 4 blocks per batch (256 blocks x 1024 thr).
// Block q owns rows [q*64, q*64+64); thread (a=tid>>5, bb=tid&31) holds
// rows q*64+a*2+{0,1}, cols bb*8..bb*8+7 in registers.
// Row pass: lane-local shfl LSE. Col pass: online (m,s) wave combine ->
// one LDS round -> per-q partial to colred (double-buffered) -> grid.sync ->
// 4-way register combine.  10 passes, then exp+mask.
// WRITE_SB=1: write bf16 S + S^T chunk-graph-major (replaces sconv).
// WRITE_SB=0: write final fp32 S.
template<int WRITE_SB>
__global__ __launch_bounds__(1024)
void sk_coop_k(float* __restrict__ S, bf16* __restrict__ S2b,
               float2* __restrict__ colred,
               const int* __restrict__ n1p, const int* __restrict__ n2p,
               const int nbl2)
{
    __shared__ float2 lw[16][256];   // 16 wave partials (each 4 rows), 32 KB
    cg::grid_group grid = cg::this_grid();
    const int bid = (int)blockIdx.x;
    const int b = bid >> 2, q = bid & 3;
    const int tid = (int)threadIdx.x;
    const int a = tid >> 5, bb = tid & 31;
    const int r0 = q * 64 + a * 2, c0 = bb * 8;
    const int n1 = n1p[b], n2 = n2p[b];
    float* Sb_ = S + ((size_t)b << 16);

    float v[2][8];
#pragma unroll
    for (int ri = 0; ri < 2; ++ri) {
        const float4* rp = (const float4*)(Sb_ + (size_t)(r0 + ri) * 256 + c0);
        const float4 x0 = rp[0], x1 = rp[1];
        v[ri][0] = x0.x; v[ri][1] = x0.y; v[ri][2] = x0.z; v[ri][3] = x0.w;
        v[ri][4] = x1.x; v[ri][5] = x1.y; v[ri][6] = x1.z; v[ri][7] = x1.w;
    }

    for (int it = 0; it < 10; ++it) {
        if ((it & 1) == 0) {
            // row LSE: local 8 + shfl_xor across the 32 bb-lanes
#pragma unroll
            for (int ri = 0; ri < 2; ++ri) {
                float m = v[ri][0];
#pragma unroll
                for (int c = 1; c < 8; ++c) m = fmaxf(m, v[ri][c]);
#pragma unroll
                for (int off = 1; off < 32; off <<= 1) m = fmaxf(m, __shfl_xor(m, off));
                float s = 0.f;
#pragma unroll
                for (int c = 0; c < 8; ++c) s += expf(v[ri][c] - m);
#pragma unroll
                for (int off = 1; off < 32; off <<= 1) s += __shfl_xor(s, off);
                const float lse = m + logf(s);
                if (r0 + ri < n1) {
#pragma unroll
                    for (int c = 0; c < 8; ++c) v[ri][c] -= lse;
                }
            }
        } else {
            const int par = (it >> 1) & 1;
            // per-thread online (m,s) over its 2 rows
            float2 loc[8];
#pragma unroll
            for (int c = 0; c < 8; ++c) {
                const float m = fmaxf(v[0][c], v[1][c]);
                loc[c].x = m;
                loc[c].y = expf(v[0][c] - m) + expf(v[1][c] - m);
            }
            // wave combine: lanes l and l^32 own the same columns (a pair)
#pragma unroll
            for (int c = 0; c < 8; ++c) {
                float2 o;
                o.x = __shfl_xor(loc[c].x, 32);
                o.y = __shfl_xor(loc[c].y, 32);
                loc[c] = lse_comb(loc[c], o);
            }
            if ((tid & 63) < 32) {
                const int wv = tid >> 6;
#pragma unroll
                for (int c = 0; c < 8; ++c) lw[wv][c0 + c] = loc[c];
            }
            __syncthreads();
            if (tid < 256) {
                float2 acc = lw[0][tid];
#pragma unroll
                for (int wv = 1; wv < 16; ++wv) acc = lse_comb(acc, lw[wv][tid]);
                colred[(((size_t)par * 64 + b) * 4 + q) * 256 + tid] = acc;
            }
            grid.sync();
            const float2* cr = colred + (((size_t)par * 64 + b) * 4) * 256;
#pragma unroll
            for (int c = 0; c < 8; ++c) {
                float2 acc = cr[c0 + c];
                acc = lse_comb(acc, cr[256 + c0 + c]);
                acc = lse_comb(acc, cr[512 + c0 + c]);
                acc = lse_comb(acc, cr[768 + c0 + c]);
                const float lse = acc.x + logf(acc.y);
                if (c0 + c < n2) { v[0][c] -= lse; v[1][c] -= lse; }
            }
        }
    }

#pragma unroll
    for (int ri = 0; ri < 2; ++ri)
#pragma unroll
        for (int c = 0; c < 8; ++c)
            v[ri][c] = (r0 + ri < n1 && c0 + c < n2) ? expf(v[ri][c]) : 0.f;

    if constexpr (WRITE_SB) {
        const int nb = 1 << nbl2;
        const int cch = b >> nbl2, ii = b & (nb - 1);
        bf16* sbB = S2b + ((size_t)((cch * 2) * nb + ii) << 16);
        bf16* stB = S2b + ((size_t)((cch * 2 + 1) * nb + ii) << 16);
#pragma unroll
        for (int ri = 0; ri < 2; ++ri) {
            union { bf16 h[8]; uint4 u; } p;
#pragma unroll
            for (int c = 0; c < 8; ++c) p.h[c] = (bf16)v[ri][c];
            *(uint4*)(sbB + (size_t)(r0 + ri) * 256 + c0) = p.u;
        }
#pragma unroll
        for (int c = 0; c < 8; ++c) {
            union { bf16 h[2]; unsigned u; } p;
            p.h[0] = (bf16)v[0][c]; p.h[1] = (bf16)v[1][c];
            *(unsigned*)(stB + (size_t)(c0 + c) * 256 + r0) = p.u;
        }
    } else {
#pragma unroll
        for (int ri = 0; ri < 2; ++ri) {
            float4 x0, x1;
            x0.x = v[ri][0]; x0.y = v[ri][1]; x0.z = v[ri][2]; x0.w = v[ri][3];
            x1.x = v[ri][4]; x1.y = v[ri][5]; x1.z = v[ri][6]; x1.w = v[ri][7];
            float4* rp = (float4*)(Sb_ + (size_t)(r0 + ri) * 256 + c0);
            rp[0] = x0; rp[1] = x1;
        }
    }
}

extern "C" void kernel_launch(void* const* d_in, const int* in_sizes, int n_in,
                              void* d_out, int out_size, void* d_ws, size_t ws_size,
                              hipStream_t stream)
{
    (void)in_sizes; (void)n_in; (void)out_size;
    const float* feat1  = (const float*)d_in[0];
    const float* feat2  = (const float*)d_in[1];
    const float* A1     = (const float*)d_in[2];
    const float* A2     = (const float*)d_in[3];
    const float* g0_aW  = (const float*)d_in[4];
    const float* g0_ab  = (const float*)d_in[5];
    const float* g0_uW  = (const float*)d_in[6];
    const float* g0_ub  = (const float*)d_in[7];
    const float* g1_aW  = (const float*)d_in[8];
    const float* g1_ab  = (const float*)d_in[9];
    const float* g1_uW  = (const float*)d_in[10];
    const float* g1_ub  = (const float*)d_in[11];
    const float* aff0_W = (const float*)d_in[12];
    const float* aff1_W = (const float*)d_in[13];
    const float* cross_W = (const float*)d_in[14];
    const float* cross_b = (const float*)d_in[15];
    const int* n1p = (const int*)d_in[16];
    const int* n2p = (const int*)d_in[17];
    const int* taup = (const int*)d_in[20];

    float* S = (float*)d_out;                     // [64,256,256] fp32 (sinkhorn in regs)

    // ---- workspace layout (base = 226,623,488 B) ----
    bf16* w = (bf16*)d_ws;
    bf16* E12b = w;   w += 67108864;              // [nc][2][nb*256][2048]
    bf16* g0aWt = w;  w += 2097152;               // [2048][1024]
    bf16* g0uWt = w;  w += 2097152;
    bf16* g1aWt = w;  w += 4194304;               // [2048][2048]
    bf16* g1uWt = w;  w += 4194304;
    bf16* aff0Wt = w; w += 4194304;
    bf16* aff1Wt = w; w += 4194304;
    bf16* cWtT = w;   w += 4194304;               // cross_W rows 0..2047, transposed
    bf16* cWbT = w;   w += 4194304;               // cross_W rows 2048..4095, transposed
    bf16* A12b = w;   w += 8388608;               // [nc][2][nb][256][256]
    bf16* S2b = w;    w += 8388608;               // [nc][2][nb][256][256] (S then S^T)
    float* rcs_cg = (float*)w; w += 65536;        // [nc][2][nb][256] fp32

    // chunk scratch: Ha (2*nb*1MB) + region2 (max of Fbc2 / H12 / Spart / colred)
    int nb = 1;
    {
        const long long avail = (long long)ws_size - 226623488LL;
        while (nb < 32 && (long long)(nb * 2) * 4194304LL <= avail) nb <<= 1;
    }
    const int nbl2 = __builtin_ctz(nb);
    const int nc = 64 / nb;
    bf16* Ha = w;                                 // [2][nb][2048][256]-T / P0,P1 halves
    bf16* region2 = Ha + (size_t)2 * nb * 524288;
    bf16* Fbc2 = region2;                         // [2][nb*256][1024]   (layer-0 only)
    bf16* H12 = region2;                          // [2][nb*256][2048]   (cross only)
    float* Spart = (float*)region2;               // [8][nb][256][256]   (affinity only)
    float2* colred = (float2*)region2;            // [2][64][4][256]     (sinkhorn only, 1MB)

    const dim3 blk(256);
    const dim3 gF2(16, nb * 2, 4);    // pair-fused row GEMM, N=2048, 128x128 tile
    const dim3 gAdd(16, 2, nb * 2);   // batched adjacency/S ADD
    const dim3 gP(32, nb * 2, 2);     // P GEMM split-K=2, 128x64 tile
    const dim3 gPart(4, 2, nb * 8);   // 8-slice affinity inner product, 128x64 tile

    const long long EC = (long long)nb * 524288;  // per-graph chunk stride (bf16 elems)
    const long long FC = (long long)nb * 262144;  // per-graph feat chunk stride
    const long long PH = (long long)nb * 524288;  // P-half stride (elems)

    // ---- prep
    wtrans_k<<<dim3(64, 32), blk, 0, stream>>>(g0_aW, g0aWt, 1024, 2048);
    wtrans_k<<<dim3(64, 32), blk, 0, stream>>>(g0_uW, g0uWt, 1024, 2048);
    wtrans_k<<<dim3(64, 64), blk, 0, stream>>>(g1_aW, g1aWt, 2048, 2048);
    wtrans_k<<<dim3(64, 64), blk, 0, stream>>>(g1_uW, g1uWt, 2048, 2048);
    wtrans_k<<<dim3(64, 64), blk, 0, stream>>>(aff0_W, aff0Wt, 2048, 2048);
    wtrans_k<<<dim3(64, 64), blk, 0, stream>>>(aff1_W, aff1Wt, 2048, 2048);
    wtrans_k<<<dim3(64, 64), blk, 0, stream>>>(cross_W, cWtT, 2048, 2048);
    wtrans_k<<<dim3(64, 64), blk, 0, stream>>>(cross_W + 4194304, cWbT, 2048, 2048);
    for (int c = 0; c < nc; ++c) {
        cvt_k<<<256, blk, 0, stream>>>((const float4*)(A1 + (long long)c * nb * 65536),
                                       (uint2*)(A12b + (long long)c * 2 * nb * 65536),
                                       (long long)nb * 16384);
        cvt_k<<<256, blk, 0, stream>>>((const float4*)(A2 + (long long)c * nb * 65536),
                                       (uint2*)(A12b + (long long)(c * 2 + 1) * nb * 65536),
                                       (long long)nb * 16384);
    }
    colsum_rcp_k<<<64, blk, 0, stream>>>(A1, rcs_cg, nbl2, 0);
    colsum_rcp_k<<<64, blk, 0, stream>>>(A2, rcs_cg, nbl2, 1);

    // ---- layer 0 Gconv + affinity 0 (chunked; graphs AND aW/uW fused via blockIdx.z)
    for (int c = 0; c < nc; ++c) {
        bf16* E12c = E12b + (long long)c * 2 * EC;
        const float* rsc = rcs_cg + (long long)c * 2 * nb * 256;
        cvt_k<<<1024, blk, 0, stream>>>((const float4*)(feat1 + (long long)c * nb * 262144),
                                        (uint2*)Fbc2, (long long)nb * 65536);
        cvt_k<<<1024, blk, 0, stream>>>((const float4*)(feat2 + (long long)c * nb * 262144),
                                        (uint2*)(Fbc2 + FC), (long long)nb * 65536);
        hgemm2_k<EPI_BIAS_RELU_SCALE_T, EPI_BIAS_RELU, false><<<gF2, blk, 0, stream>>>(
            Fbc2, g0aWt, g0uWt, Ha, E12c, nb * 256, 2048, 1024,
            FC, EC, EC, nb * 256, g0_ab, g0_ub, rsc);
        hgemm_k<EPI_ADD, bf16, 4><<<gAdd, blk, 0, stream>>>(               // E += A @ ax
            A12b + (long long)c * 2 * nb * 65536, Ha, E12c, 256, 2048, 256,
            65536, 524288, 524288, 0, nullptr);
        hgemm_k<EPI_PARTP, bf16, 2><<<gP, blk, 0, stream>>>(               // P0,P1 = E1@aff0W (split-K)
            E12c, aff0Wt, Ha, nb * 256, 2048, 2048, 0, 0, PH, 0, nullptr);
        hgemm_k<EPI_PART, float, 2><<<gPart, blk, 0, stream>>>(            // Spart = (P0+P1)@E2^T
            Ha, E12c + EC, Spart, 256, 256, 2048, 524288, 524288, 65536, PH, nullptr);
        mask_tau_red_k<<<nb * 256, blk, 0, stream>>>(
            Spart, S + (long long)c * nb * 65536, n1p + c * nb, n2p + c * nb, taup, nb);
    }
    {
        float* S_ = S; bf16* S2b_ = S2b; float2* cr_ = colred;
        const int* n1_ = n1p; const int* n2_ = n2p; int nbl2_ = nbl2;
        void* args[6] = { &S_, &S2b_, &cr_, &n1_, &n2_, &nbl2_ };
        void (*fp)(float*, bf16*, float2*, const int*, const int*, int) = sk_coop_k<1>;
        hipLaunchCooperativeKernel(reinterpret_cast<const void*>(fp),
                                   dim3(256), dim3(1024), args, 0, stream);
    }

    // ---- cross update + layer 1 + affinity 1 (chunked, pair-fused)
    for (int c = 0; c < nc; ++c) {
        bf16* E12c = E12b + (long long)c * 2 * EC;
        const float* rsc = rcs_cg + (long long)c * 2 * nb * 256;
        // Ha[g]=(E_{g^1}@cWb)^T ; H12[g]=E_g@cWt+b   [one dispatch, z=4, SWAPA0]
        hgemm2_k<EPI_STORE_T, EPI_BIAS, true><<<gF2, blk, 0, stream>>>(
            E12c, cWbT, cWtT, Ha, H12, nb * 256, 2048, 2048,
            EC, EC, EC, 0, nullptr, cross_b, nullptr);
        // H12[0] += S@Ha[0], H12[1] += S^T@Ha[1]
        hgemm_k<EPI_ADD, bf16, 4><<<gAdd, blk, 0, stream>>>(
            S2b + (long long)c * 2 * nb * 65536, Ha, H12, 256, 2048, 256,
            65536, 524288, 524288, 0, nullptr);
        // layer 1: Ha = (rcs*relu(H12@aW+b))^T ; E = relu(H12@uW+b)
        hgemm2_k<EPI_BIAS_RELU_SCALE_T, EPI_BIAS_RELU, false><<<gF2, blk, 0, stream>>>(
            H12, g1aWt, g1uWt, Ha, E12c, nb * 256, 2048, 2048,
            EC, EC, EC, nb * 256, g1_ab, g1_ub, rsc);
        hgemm_k<EPI_ADD, bf16, 4><<<gAdd, blk, 0, stream>>>(
            A12b + (long long)c * 2 * nb * 65536, Ha, E12c, 256, 2048, 256,
            65536, 524288, 524288, 0, nullptr);
        // affinity 1
        hgemm_k<EPI_PARTP, bf16, 2><<<gP, blk, 0, stream>>>(
            E12c, aff1Wt, Ha, nb * 256, 2048, 2048, 0, 0, PH, 0, nullptr);
        hgemm_k<EPI_PART, float, 2><<<gPart, blk, 0, stream>>>(
            Ha, E12c + EC, Spart, 256, 256, 2048, 524288, 524288, 65536, PH, nullptr);
        mask_tau_red_k<<<nb * 256, blk, 0, stream>>>(
            Spart, S + (long long)c * nb * 65536, n1p + c * nb, n2p + c * nb, taup, nb);
    }
    {
        float* S_ = S; bf16* S2b_ = nullptr; float2* cr_ = colred;
        const int* n1_ = n1p; const int* n2_ = n2p; int nbl2_ = 0;
        void* args[6] = { &S_, &S2b_, &cr_, &n1_, &n2_, &nbl2_ };
        void (*fp)(float*, bf16*, float2*, const int*, const int*, int) = sk_coop_k<0>;
        hipLaunchCooperativeKernel(reinterpret_cast<const void*>(fp),
                                   dim3(256), dim3(1024), args, 0, stream);
    }
}

// Round 6
// 3472.581 us; speedup vs baseline: 1.0822x; 1.0822x over previous
//
#include <hip/hip_runtime.h>
#include <cstdint>
#include <cstddef>

typedef __bf16 bf16;
typedef float f32x4 __attribute__((ext_vector_type(4)));
typedef bf16  bf16x8 __attribute__((ext_vector_type(8)));

#define NEGV (-1e30f)

// B=64, N=256, IN=1024, HID=OUT=2048
enum { EPI_STORE = 0, EPI_ADD = 1, EPI_BIAS_RELU = 2, EPI_BIAS = 3,
       EPI_STORE_T = 5, EPI_BIAS_RELU_SCALE_T = 6, EPI_PART = 7, EPI_PARTP = 8 };

__device__ __forceinline__ void gload16(const void* g, void* l) {
    __builtin_amdgcn_global_load_lds((const __attribute__((address_space(1))) void*)g,
                                     (__attribute__((address_space(3))) void*)l, 16, 0, 0);
}

// bf16 MFMA GEMM (m97 structure): C[bz] = epi(A[bz] @ B[bz]^T-layout)
// A: [M][K] bf16 row-major.  B: NT layout [N][K] bf16 row-major.
// Tile: 128 x (NTJ*32).  NTJ=4 -> 128x128; NTJ=2 -> 128x64 (4 waves).
// z-batching: ptr += bz * s{A,B,C}.
// EPI_PART: 8 K-slices over two partial-sum A buffers (halves at stride sH):
//   bz = batch*8 + ks; h = ks>>2 selects A-half, kk = ks&3 selects K/4 range;
//   output slice C + (ks*nbatch + batch)*sC  (nbatch = gridDim.z/8).
// EPI_PARTP: split-K=2 producer; bz selects K-half; C += bz*sC (partial sums).
template<int EPI, typename CT, int NTJ>
__global__ __launch_bounds__(256, 2)
void hgemm_k(const bf16* __restrict__ Ab, const bf16* __restrict__ Bb,
             CT* __restrict__ Cb, const int M, const int N, const int K,
             const long long sA, const long long sB, const long long sC,
             const long long sH, const float* __restrict__ bias)
{
    __shared__ bf16 Asl[128 * 32];
    __shared__ bf16 Bsl[NTJ * 32 * 32];
    const int bz = (int)blockIdx.z;
    int ba = bz, kbeg = 0, klen = K;
    long long aoff = 0;
    if constexpr (EPI == EPI_PART) {
        ba = bz >> 3;
        const int ks = bz & 7;
        kbeg = (ks & 3) * (K >> 2); klen = K >> 2;
        aoff = (long long)(ks >> 2) * sH;
    }
    if constexpr (EPI == EPI_PARTP) {
        ba = 0; kbeg = bz * (K >> 1); klen = K >> 1;
    }
    const bf16* __restrict__ A = Ab + (long long)ba * sA + aoff;
    const bf16* __restrict__ B = Bb + (long long)ba * sB;
    CT* __restrict__ C;
    if constexpr (EPI == EPI_PART)
        C = Cb + (long long)((bz & 7) * ((int)gridDim.z >> 3) + (bz >> 3)) * sC;
    else
        C = Cb + (long long)bz * sC;

    const int m0 = blockIdx.y * 128, n0 = blockIdx.x * (NTJ * 32);
    const int tid = (int)threadIdx.x;
    const int lane = tid & 63, wave = tid >> 6;
    const int wm = (wave & 1) * 64, wn = (wave >> 1) * (NTJ * 16);
    const int lrow = lane & 15, quad = lane >> 4;

    f32x4 acc[4][NTJ];
    const f32x4 zero = {0.f, 0.f, 0.f, 0.f};
#pragma unroll
    for (int i = 0; i < 4; ++i)
#pragma unroll
        for (int j = 0; j < NTJ; ++j) acc[i][j] = zero;

    const int sr = tid >> 2, sck = (tid & 3) * 8;
    const bf16* ga0 = A + (long long)(m0 + sr) * K + kbeg + sck;
    const bf16* ga1 = ga0 + (long long)64 * K;
    const bf16* gb0 = B + (long long)(n0 + sr) * K + kbeg + sck;
    const bf16* gb1 = gb0 + (long long)64 * K;      // NTJ==4 only
    bf16* la0 = Asl + tid * 8;
    bf16* la1 = Asl + 2048 + tid * 8;
    bf16* lb0 = Bsl + tid * 8;
    bf16* lb1 = Bsl + 2048 + tid * 8;               // NTJ==4 only
    const bf16* ar = Asl + (wm + lrow) * 32 + quad * 8;
    const bf16* br = Bsl + (wn + lrow) * 32 + quad * 8;

    for (int k0 = 0; k0 < klen; k0 += 32) {
        gload16(ga0, la0); gload16(ga1, la1);
        gload16(gb0, lb0);
        if constexpr (NTJ == 4) gload16(gb1, lb1);
        ga0 += 32; ga1 += 32; gb0 += 32; gb1 += 32;
        __syncthreads();
        bf16x8 af[4], bfr[NTJ];
#pragma unroll
        for (int t = 0; t < 4; ++t) af[t] = *(const bf16x8*)(ar + t * 512);
#pragma unroll
        for (int t = 0; t < NTJ; ++t) bfr[t] = *(const bf16x8*)(br + t * 512);
#pragma unroll
        for (int i = 0; i < 4; ++i)
#pragma unroll
            for (int j = 0; j < NTJ; ++j)
                acc[i][j] = __builtin_amdgcn_mfma_f32_16x16x32_bf16(af[i], bfr[j], acc[i][j], 0, 0, 0);
        __syncthreads();
    }

    // C/D layout: col = lane&15, row = quad*4 + reg   [m89-verified]
#pragma unroll
    for (int ti = 0; ti < 4; ++ti) {
        const int gm0 = m0 + wm + ti * 16 + quad * 4;
#pragma unroll
        for (int r = 0; r < 4; ++r) {
            const int gm = gm0 + r;
#pragma unroll
            for (int tj = 0; tj < NTJ; ++tj) {
                const int gn = n0 + wn + tj * 16 + lrow;
                const float v = acc[ti][tj][r];
                CT* cp = C + (size_t)gm * N + gn;
                if constexpr (EPI == EPI_STORE)          *cp = (CT)v;
                else if constexpr (EPI == EPI_PART)      *cp = (CT)v;
                else if constexpr (EPI == EPI_PARTP)     *cp = (CT)v;
                else if constexpr (EPI == EPI_ADD)       *cp = (CT)((float)*cp + v);
                else if constexpr (EPI == EPI_BIAS_RELU) *cp = (CT)fmaxf(v + bias[gn], 0.f);
                else if constexpr (EPI == EPI_BIAS)      *cp = (CT)(v + bias[gn]);
            }
        }
    }
}

// Paired-output GEMM: two N=2048 GEMMs sharing the A operand, fused via z.
// z in [0,4): g = z&1 (graph), w = z>>1 (which B/epilogue).
//   w=0: B=B0, epilogue EPI0 (T-type) -> C0 + g*sC0
//   w=1: B=B1, epilogue EPI1 (row-major) -> C1 + g*sC1
// A = Ab + sel*sA, sel = (w==0 && SWAPA0) ? g^1 : g.
// T-epilogue writes per-256-row-batch transposed: C[b][n][m] (b = gm>>8).
template<int EPI0, int EPI1, bool SWAPA0>
__global__ __launch_bounds__(256, 2)
void hgemm2_k(const bf16* __restrict__ Ab,
              const bf16* __restrict__ B0b, const bf16* __restrict__ B1b,
              bf16* __restrict__ C0b, bf16* __restrict__ C1b,
              const int M, const int N, const int K,
              const long long sA, const long long sC0, const long long sC1,
              const long long sR,
              const float* __restrict__ bias0, const float* __restrict__ bias1,
              const float* __restrict__ rowscale)
{
    __shared__ bf16 Asl[128 * 32];
    __shared__ bf16 Bsl[128 * 32];
    const int bz = (int)blockIdx.z;
    const int g = bz & 1, wsel = bz >> 1;
    const int asel = (wsel == 0 && SWAPA0) ? (g ^ 1) : g;
    const bf16* __restrict__ A = Ab + (long long)asel * sA;
    const bf16* __restrict__ B = wsel ? B1b : B0b;
    bf16* __restrict__ C = wsel ? (C1b + (long long)g * sC1)
                                : (C0b + (long long)g * sC0);
    const float* __restrict__ bias = wsel ? bias1 : bias0;
    const float* __restrict__ rs = rowscale + (long long)g * sR;

    const int m0 = blockIdx.y * 128, n0 = blockIdx.x * 128;
    const int tid = (int)threadIdx.x;
    const int lane = tid & 63, wave = tid >> 6;
    const int wm = (wave & 1) * 64, wn = (wave >> 1) * 64;
    const int lrow = lane & 15, quad = lane >> 4;

    f32x4 acc[4][4];
    const f32x4 zero = {0.f, 0.f, 0.f, 0.f};
#pragma unroll
    for (int i = 0; i < 4; ++i)
#pragma unroll
        for (int j = 0; j < 4; ++j) acc[i][j] = zero;

    const int sr = tid >> 2, sck = (tid & 3) * 8;
    const bf16* ga0 = A + (long long)(m0 + sr) * K + sck;
    const bf16* ga1 = ga0 + (long long)64 * K;
    const bf16* gb0 = B + (long long)(n0 + sr) * K + sck;
    const bf16* gb1 = gb0 + (long long)64 * K;
    bf16* la0 = Asl + tid * 8;
    bf16* la1 = Asl + 2048 + tid * 8;
    bf16* lb0 = Bsl + tid * 8;
    bf16* lb1 = Bsl + 2048 + tid * 8;
    const bf16* ar = Asl + (wm + lrow) * 32 + quad * 8;
    const bf16* br = Bsl + (wn + lrow) * 32 + quad * 8;

    for (int k0 = 0; k0 < K; k0 += 32) {
        gload16(ga0, la0); gload16(ga1, la1);
        gload16(gb0, lb0); gload16(gb1, lb1);
        ga0 += 32; ga1 += 32; gb0 += 32; gb1 += 32;
        __syncthreads();
        bf16x8 af[4], bfr[4];
#pragma unroll
        for (int t = 0; t < 4; ++t) {
            af[t]  = *(const bf16x8*)(ar + t * 512);
            bfr[t] = *(const bf16x8*)(br + t * 512);
        }
#pragma unroll
        for (int i = 0; i < 4; ++i)
#pragma unroll
            for (int j = 0; j < 4; ++j)
                acc[i][j] = __builtin_amdgcn_mfma_f32_16x16x32_bf16(af[i], bfr[j], acc[i][j], 0, 0, 0);
        __syncthreads();
    }

    if (wsel == 0) {
        // T-epilogue: per-256-row-batch transposed, packed 4x bf16 along m
#pragma unroll
        for (int ti = 0; ti < 4; ++ti) {
            const int gm0 = m0 + wm + ti * 16 + quad * 4;
#pragma unroll
            for (int tj = 0; tj < 4; ++tj) {
                const int gn = n0 + wn + tj * 16 + lrow;
                union { bf16 h[4]; uint2 u; } p;
#pragma unroll
                for (int r = 0; r < 4; ++r) {
                    float v = acc[ti][tj][r];
                    if constexpr (EPI0 == EPI_BIAS_RELU_SCALE_T)
                        v = fmaxf(v + bias[gn], 0.f) * rs[gm0 + r];
                    p.h[r] = (bf16)v;
                }
                *(uint2*)(C + ((size_t)(gm0 >> 8)) * 524288 +
                          (size_t)gn * 256 + (gm0 & 255)) = p.u;
            }
        }
    } else {
#pragma unroll
        for (int ti = 0; ti < 4; ++ti) {
            const int gm0 = m0 + wm + ti * 16 + quad * 4;
#pragma unroll
            for (int r = 0; r < 4; ++r) {
                const int gm = gm0 + r;
#pragma unroll
                for (int tj = 0; tj < 4; ++tj) {
                    const int gn = n0 + wn + tj * 16 + lrow;
                    const float v = acc[ti][tj][r];
                    bf16* cp = C + (size_t)gm * N + gn;
                    if constexpr (EPI1 == EPI_BIAS_RELU) *cp = (bf16)fmaxf(v + bias[gn], 0.f);
                    else                                 *cp = (bf16)(v + bias[gn]);
                }
            }
        }
    }
}

// fp32 [K][N] -> bf16 [N][K]  (weight transpose-convert)
__global__ __launch_bounds__(256)
void wtrans_k(const float* __restrict__ W, bf16* __restrict__ Wt, const int K, const int N)
{
    __shared__ float tl[32][33];
    const int k0 = blockIdx.y * 32, n0 = blockIdx.x * 32;
    const int tx = (int)threadIdx.x & 31, ty = (int)threadIdx.x >> 5;
#pragma unroll
    for (int q = 0; q < 4; ++q)
        tl[ty + 8 * q][tx] = W[(size_t)(k0 + ty + 8 * q) * N + n0 + tx];
    __syncthreads();
#pragma unroll
    for (int q = 0; q < 4; ++q)
        Wt[(size_t)(n0 + ty + 8 * q) * K + k0 + tx] = (bf16)tl[tx][ty + 8 * q];
}

// fp32 -> bf16 elementwise (vectorized)
__global__ __launch_bounds__(256)
void cvt_k(const float4* __restrict__ in, uint2* __restrict__ out, const long long n4)
{
    long long i = (long long)blockIdx.x * 256 + threadIdx.x;
    const long long st = (long long)gridDim.x * 256;
    for (; i < n4; i += st) {
        const float4 v = in[i];
        union { bf16 h[4]; uint2 u; } p;
        p.h[0] = (bf16)v.x; p.h[1] = (bf16)v.y; p.h[2] = (bf16)v.z; p.h[3] = (bf16)v.w;
        out[i] = p.u;
    }
}

// rcs_cg[((b>>nbl2)*2+g)*nb + (b&(nb-1))][j] = 1 / max(sum_i |A[b,i,j]|, 1e-12)
__global__ __launch_bounds__(256)
void colsum_rcp_k(const float* __restrict__ A, float* __restrict__ rcs,
                  const int nbl2, const int g)
{
    const int b = blockIdx.x, j = (int)threadIdx.x;
    const int cch = b >> nbl2, ii = b & ((1 << nbl2) - 1), nb = 1 << nbl2;
    const float* p = A + (size_t)b * 65536;
    float s = 0.f;
    for (int i = 0; i < 256; ++i) s += fabsf(p[i * 256 + j]);
    rcs[(size_t)((cch * 2 + g) * nb + ii) * 256 + j] = 1.f / fmaxf(s, 1e-12f);
}

// online logsumexp partial merge: (m,s) x (m,s) -> (m,s)
__device__ __forceinline__ float2 lse_comb(float2 x, float2 y) {
    const float M = fmaxf(x.x, y.x);
    float2 r; r.x = M; r.y = x.y * expf(x.x - M) + y.y * expf(y.x - M);
    return r;
}

// Fused mask/tau/Spart-reduce + FIRST row-LSE pass (sinkhorn it=0).
// One chunk (nb batches): grid nb*64 blocks x 256 thr, one 64-lane wave per row.
__global__ __launch_bounds__(256)
void sk_mrow_k(const float* __restrict__ Sp, float* __restrict__ S,
               const int* __restrict__ n1p, const int* __restrict__ n2p,
               const int* __restrict__ taup, const int nb)
{
    const int w = (int)threadIdx.x >> 6, lane = (int)threadIdx.x & 63;
    const int rowg = blockIdx.x * 4 + w;          // [0, nb*256)
    const int b = rowg >> 8, i = rowg & 255;
    const int n1 = n1p[b], n2 = n2p[b];
    const float tau = (float)taup[0];
    const size_t stride = (size_t)nb << 16;
    const size_t base = (size_t)rowg * 256 + (size_t)lane * 4;
    float4 s4 = {0.f, 0.f, 0.f, 0.f};
#pragma unroll
    for (int ks = 0; ks < 8; ++ks) {
        const float4 t = *(const float4*)(Sp + ks * stride + base);
        s4.x += t.x; s4.y += t.y; s4.z += t.z; s4.w += t.w;
    }
    const int j0 = lane * 4;
    float4 v;
    v.x = (i < n1 && j0 + 0 < n2) ? s4.x / tau : NEGV;
    v.y = (i < n1 && j0 + 1 < n2) ? s4.y / tau : NEGV;
    v.z = (i < n1 && j0 + 2 < n2) ? s4.z / tau : NEGV;
    v.w = (i < n1 && j0 + 3 < n2) ? s4.w / tau : NEGV;
    float m = fmaxf(fmaxf(v.x, v.y), fmaxf(v.z, v.w));
#pragma unroll
    for (int off = 32; off > 0; off >>= 1) m = fmaxf(m, __shfl_down(m, off));
    m = __shfl(m, 0);
    float s = expf(v.x - m) + expf(v.y - m) + expf(v.z - m) + expf(v.w - m);
#pragma unroll
    for (int off = 32; off > 0; off >>= 1) s += __shfl_down(s, off);
    s = __shfl(s, 0);
    const float lse = m + logf(s);
    if (i < n1) { v.x -= lse; v.y -= lse; v.z -= lse; v.w -= lse; }
    *(float4*)(S + base) = v;
}

// Row logsumexp pass: one 64-lane wave per row (full S: 4096 blocks).
__global__ __launch_bounds__(256)
void sk_row_k(float* __restrict__ S, const int* __restrict__ n1p)
{
    const int w = (int)threadIdx.x >> 6, lane = (int)threadIdx.x & 63;
    const int rowg = blockIdx.x * 4 + w;
    const int b = rowg >> 8, i = rowg & 255;
    float* p = S + (size_t)rowg * 256;
    float4 v = ((const float4*)p)[lane];
    float m = fmaxf(fmaxf(v.x, v.y), fmaxf(v.z, v.w));
#pragma unroll
    for (int off = 32; off > 0; off >>= 1) m = fmaxf(m, __shfl_down(m, off));
    m = __shfl(m, 0);
    float s = expf(v.x - m) + expf(v.y - m) + expf(v.z - m) + expf(v.w - m);
#pragma unroll
    for (int off = 32; off > 0; off >>= 1) s += __shfl_down(s, off);
    s = __shfl(s, 0);
    const float lse = m + logf(s);
    if (i < n1p[b]) {
        v.x -= lse; v.y -= lse; v.z -= lse; v.w -= lse;
        ((float4*)p)[lane] = v;
    }
}

// Column logsumexp pass: 256 blocks (64 batches x 4 col-chunks) x 256 thr.
// Thread t: column j = chunk*64 + (t&63); rows (t>>6)*64 .. +63 in registers
// (statically indexed v[64]); LDS (m,s) combine across 4 row-chunks.
__global__ __launch_bounds__(256)
void sk_col2_k(float* __restrict__ S, const int* __restrict__ n2p)
{
    __shared__ float2 part[4][64];
    __shared__ float lsev[64];
    const int bid = (int)blockIdx.x;
    const int b = bid >> 2, c0 = (bid & 3) * 64;
    const int t = (int)threadIdx.x, j = c0 + (t & 63), q = t >> 6;
    float* base = S + ((size_t)b << 16) + (size_t)q * 16384 + j;
    float v[64];
#pragma unroll
    for (int i = 0; i < 64; ++i) v[i] = base[i * 256];
    float m = v[0];
#pragma unroll
    for (int i = 1; i < 64; ++i) m = fmaxf(m, v[i]);
    float s = 0.f;
#pragma unroll
    for (int i = 0; i < 64; ++i) s += expf(v[i] - m);
    part[q][t & 63] = make_float2(m, s);
    __syncthreads();
    if (t < 64) {
        float2 a = part[0][t];
        a = lse_comb(a, part[1][t]);
        a = lse_comb(a, part[2][t]);
        a = lse_comb(a, part[3][t]);
        lsev[t] = a.x + logf(a.y);
    }
    __syncthreads();
    if (j < n2p[b]) {
        const float l = lsev[t & 63];
#pragma unroll
        for (int i = 0; i < 64; ++i) base[i * 256] = v[i] - l;
    }
}

// Final col pass (it=9) fused with exp+mask and output writes.
// WRITE_SB=1: bf16 S + S^T chunk-graph-major (replaces sconv), S fp32 untouched.
// WRITE_SB=0: final fp32 S (output).
template<int WRITE_SB>
__global__ __launch_bounds__(256)
void sk_fin_k(float* __restrict__ S, bf16* __restrict__ S2b,
              const int* __restrict__ n1p, const int* __restrict__ n2p,
              const int nbl2)
{
    __shared__ float2 part[4][64];
    __shared__ float lsev[64];
    const int bid = (int)blockIdx.x;
    const int b = bid >> 2, c0 = (bid & 3) * 64;
    const int t = (int)threadIdx.x, j = c0 + (t & 63), q = t >> 6;
    float* base = S + ((size_t)b << 16) + (size_t)q * 16384 + j;
    float v[64];
#pragma unroll
    for (int i = 0; i < 64; ++i) v[i] = base[i * 256];
    float m = v[0];
#pragma unroll
    for (int i = 1; i < 64; ++i) m = fmaxf(m, v[i]);
    float s = 0.f;
#pragma unroll
    for (int i = 0; i < 64; ++i) s += expf(v[i] - m);
    part[q][t & 63] = make_float2(m, s);
    __syncthreads();
    if (t < 64) {
        float2 a = part[0][t];
        a = lse_comb(a, part[1][t]);
        a = lse_comb(a, part[2][t]);
        a = lse_comb(a, part[3][t]);
        lsev[t] = a.x + logf(a.y);
    }
    __syncthreads();
    const int n1 = n1p[b];
    const bool jv = j < n2p[b];
    const float l = jv ? lsev[t & 63] : 0.f;
#pragma unroll
    for (int i = 0; i < 64; ++i) {
        const int row = q * 64 + i;
        v[i] = (row < n1 && jv) ? expf(v[i] - l) : 0.f;
    }
    if constexpr (WRITE_SB) {
        const int nb = 1 << nbl2;
        const int cch = b >> nbl2, ii = b & (nb - 1);
        bf16* sbB = S2b + ((size_t)((cch * 2) * nb + ii) << 16);
        bf16* stB = S2b + ((size_t)((cch * 2 + 1) * nb + ii) << 16);
#pragma unroll
        for (int i = 0; i < 64; ++i)
            sbB[(size_t)(q * 64 + i) * 256 + j] = (bf16)v[i];
#pragma unroll
        for (int w8 = 0; w8 < 8; ++w8) {
            union { bf16 h[8]; uint4 uu; } pk;
#pragma unroll
            for (int e = 0; e < 8; ++e) pk.h[e] = (bf16)v[w8 * 8 + e];
            *(uint4*)(stB + (size_t)j * 256 + q * 64 + w8 * 8) = pk.uu;
        }
    } else {
#pragma unroll
        for (int i = 0; i < 64; ++i) base[i * 256] = v[i];
    }
}

extern "C" void kernel_launch(void* const* d_in, const int* in_sizes, int n_in,
                              void* d_out, int out_size, void* d_ws, size_t ws_size,
                              hipStream_t stream)
{
    (void)in_sizes; (void)n_in; (void)out_size;
    const float* feat1  = (const float*)d_in[0];
    const float* feat2  = (const float*)d_in[1];
    const float* A1     = (const float*)d_in[2];
    const float* A2     = (const float*)d_in[3];
    const float* g0_aW  = (const float*)d_in[4];
    const float* g0_ab  = (const float*)d_in[5];
    const float* g0_uW  = (const float*)d_in[6];
    const float* g0_ub  = (const float*)d_in[7];
    const float* g1_aW  = (const float*)d_in[8];
    const float* g1_ab  = (const float*)d_in[9];
    const float* g1_uW  = (const float*)d_in[10];
    const float* g1_ub  = (const float*)d_in[11];
    const float* aff0_W = (const float*)d_in[12];
    const float* aff1_W = (const float*)d_in[13];
    const float* cross_W = (const float*)d_in[14];
    const float* cross_b = (const float*)d_in[15];
    const int* n1p = (const int*)d_in[16];
    const int* n2p = (const int*)d_in[17];
    const int* taup = (const int*)d_in[20];

    float* S = (float*)d_out;                     // [64,256,256] fp32

    // ---- workspace layout (base = 226,623,488 B) ----
    bf16* w = (bf16*)d_ws;
    bf16* E12b = w;   w += 67108864;              // [nc][2][nb*256][2048]
    bf16* g0aWt = w;  w += 2097152;               // [2048][1024]
    bf16* g0uWt = w;  w += 2097152;
    bf16* g1aWt = w;  w += 4194304;               // [2048][2048]
    bf16* g1uWt = w;  w += 4194304;
    bf16* aff0Wt = w; w += 4194304;
    bf16* aff1Wt = w; w += 4194304;
    bf16* cWtT = w;   w += 4194304;               // cross_W rows 0..2047, transposed
    bf16* cWbT = w;   w += 4194304;               // cross_W rows 2048..4095, transposed
    bf16* A12b = w;   w += 8388608;               // [nc][2][nb][256][256]
    bf16* S2b = w;    w += 8388608;               // [nc][2][nb][256][256] (S then S^T)
    float* rcs_cg = (float*)w; w += 65536;        // [nc][2][nb][256] fp32

    // chunk scratch: Ha (2*nb*1MB) + region2 (max of Fbc2 / H12 / Spart)
    int nb = 1;
    {
        const long long avail = (long long)ws_size - 226623488LL;
        while (nb < 32 && (long long)(nb * 2) * 4194304LL <= avail) nb <<= 1;
    }
    const int nbl2 = __builtin_ctz(nb);
    const int nc = 64 / nb;
    bf16* Ha = w;                                 // [2][nb][2048][256]-T / P0,P1 halves
    bf16* region2 = Ha + (size_t)2 * nb * 524288;
    bf16* Fbc2 = region2;                         // [2][nb*256][1024]   (layer-0 only)
    bf16* H12 = region2;                          // [2][nb*256][2048]   (cross only)
    float* Spart = (float*)region2;               // [8][nb][256][256]   (affinity only)

    const dim3 blk(256);
    const dim3 gF2(16, nb * 2, 4);    // pair-fused row GEMM, N=2048, 128x128 tile
    const dim3 gAdd(16, 2, nb * 2);   // batched adjacency/S ADD
    const dim3 gP(32, nb * 2, 2);     // P GEMM split-K=2, 128x64 tile
    const dim3 gPart(4, 2, nb * 8);   // 8-slice affinity inner product, 128x64 tile

    const long long EC = (long long)nb * 524288;  // per-graph chunk stride (bf16 elems)
    const long long FC = (long long)nb * 262144;  // per-graph feat chunk stride
    const long long PH = (long long)nb * 524288;  // P-half stride (elems)

    // ---- prep
    wtrans_k<<<dim3(64, 32), blk, 0, stream>>>(g0_aW, g0aWt, 1024, 2048);
    wtrans_k<<<dim3(64, 32), blk, 0, stream>>>(g0_uW, g0uWt, 1024, 2048);
    wtrans_k<<<dim3(64, 64), blk, 0, stream>>>(g1_aW, g1aWt, 2048, 2048);
    wtrans_k<<<dim3(64, 64), blk, 0, stream>>>(g1_uW, g1uWt, 2048, 2048);
    wtrans_k<<<dim3(64, 64), blk, 0, stream>>>(aff0_W, aff0Wt, 2048, 2048);
    wtrans_k<<<dim3(64, 64), blk, 0, stream>>>(aff1_W, aff1Wt, 2048, 2048);
    wtrans_k<<<dim3(64, 64), blk, 0, stream>>>(cross_W, cWtT, 2048, 2048);
    wtrans_k<<<dim3(64, 64), blk, 0, stream>>>(cross_W + 4194304, cWbT, 2048, 2048);
    for (int c = 0; c < nc; ++c) {
        cvt_k<<<256, blk, 0, stream>>>((const float4*)(A1 + (long long)c * nb * 65536),
                                       (uint2*)(A12b + (long long)c * 2 * nb * 65536),
                                       (long long)nb * 16384);
        cvt_k<<<256, blk, 0, stream>>>((const float4*)(A2 + (long long)c * nb * 65536),
                                       (uint2*)(A12b + (long long)(c * 2 + 1) * nb * 65536),
                                       (long long)nb * 16384);
    }
    colsum_rcp_k<<<64, blk, 0, stream>>>(A1, rcs_cg, nbl2, 0);
    colsum_rcp_k<<<64, blk, 0, stream>>>(A2, rcs_cg, nbl2, 1);

    // ---- layer 0 Gconv + affinity 0 (chunked; graphs AND aW/uW fused via blockIdx.z)
    for (int c = 0; c < nc; ++c) {
        bf16* E12c = E12b + (long long)c * 2 * EC;
        const float* rsc = rcs_cg + (long long)c * 2 * nb * 256;
        cvt_k<<<1024, blk, 0, stream>>>((const float4*)(feat1 + (long long)c * nb * 262144),
                                        (uint2*)Fbc2, (long long)nb * 65536);
        cvt_k<<<1024, blk, 0, stream>>>((const float4*)(feat2 + (long long)c * nb * 262144),
                                        (uint2*)(Fbc2 + FC), (long long)nb * 65536);
        hgemm2_k<EPI_BIAS_RELU_SCALE_T, EPI_BIAS_RELU, false><<<gF2, blk, 0, stream>>>(
            Fbc2, g0aWt, g0uWt, Ha, E12c, nb * 256, 2048, 1024,
            FC, EC, EC, nb * 256, g0_ab, g0_ub, rsc);
        hgemm_k<EPI_ADD, bf16, 4><<<gAdd, blk, 0, stream>>>(               // E += A @ ax
            A12b + (long long)c * 2 * nb * 65536, Ha, E12c, 256, 2048, 256,
            65536, 524288, 524288, 0, nullptr);
        hgemm_k<EPI_PARTP, bf16, 2><<<gP, blk, 0, stream>>>(               // P0,P1 = E1@aff0W (split-K)
            E12c, aff0Wt, Ha, nb * 256, 2048, 2048, 0, 0, PH, 0, nullptr);
        hgemm_k<EPI_PART, float, 2><<<gPart, blk, 0, stream>>>(            // Spart = (P0+P1)@E2^T
            Ha, E12c + EC, Spart, 256, 256, 2048, 524288, 524288, 65536, PH, nullptr);
        sk_mrow_k<<<nb * 64, blk, 0, stream>>>(                            // mask/tau + row it0
            Spart, S + (long long)c * nb * 65536, n1p + c * nb, n2p + c * nb, taup, nb);
    }
    for (int p = 0; p < 4; ++p) {                 // it1..it8
        sk_col2_k<<<256, blk, 0, stream>>>(S, n2p);
        sk_row_k<<<4096, blk, 0, stream>>>(S, n1p);
    }
    sk_fin_k<1><<<256, blk, 0, stream>>>(S, S2b, n1p, n2p, nbl2);   // it9 col + exp + S/S^T bf16

    // ---- cross update + layer 1 + affinity 1 (chunked, pair-fused)
    for (int c = 0; c < nc; ++c) {
        bf16* E12c = E12b + (long long)c * 2 * EC;
        const float* rsc = rcs_cg + (long long)c * 2 * nb * 256;
        // Ha[g]=(E_{g^1}@cWb)^T ; H12[g]=E_g@cWt+b   [one dispatch, z=4, SWAPA0]
        hgemm2_k<EPI_STORE_T, EPI_BIAS, true><<<gF2, blk, 0, stream>>>(
            E12c, cWbT, cWtT, Ha, H12, nb * 256, 2048, 2048,
            EC, EC, EC, 0, nullptr, cross_b, nullptr);
        // H12[0] += S@Ha[0], H12[1] += S^T@Ha[1]
        hgemm_k<EPI_ADD, bf16, 4><<<gAdd, blk, 0, stream>>>(
            S2b + (long long)c * 2 * nb * 65536, Ha, H12, 256, 2048, 256,
            65536, 524288, 524288, 0, nullptr);
        // layer 1: Ha = (rcs*relu(H12@aW+b))^T ; E = relu(H12@uW+b)
        hgemm2_k<EPI_BIAS_RELU_SCALE_T, EPI_BIAS_RELU, false><<<gF2, blk, 0, stream>>>(
            H12, g1aWt, g1uWt, Ha, E12c, nb * 256, 2048, 2048,
            EC, EC, EC, nb * 256, g1_ab, g1_ub, rsc);
        hgemm_k<EPI_ADD, bf16, 4><<<gAdd, blk, 0, stream>>>(
            A12b + (long long)c * 2 * nb * 65536, Ha, E12c, 256, 2048, 256,
            65536, 524288, 524288, 0, nullptr);
        // affinity 1
        hgemm_k<EPI_PARTP, bf16, 2><<<gP, blk, 0, stream>>>(
            E12c, aff1Wt, Ha, nb * 256, 2048, 2048, 0, 0, PH, 0, nullptr);
        hgemm_k<EPI_PART, float, 2><<<gPart, blk, 0, stream>>>(
            Ha, E12c + EC, Spart, 256, 256, 2048, 524288, 524288, 65536, PH, nullptr);
        sk_mrow_k<<<nb * 64, blk, 0, stream>>>(
            Spart, S + (long long)c * nb * 65536, n1p + c * nb, n2p + c * nb, taup, nb);
    }
    for (int p = 0; p < 4; ++p) {
        sk_col2_k<<<256, blk, 0, stream>>>(S, n2p);
        sk_row_k<<<4096, blk, 0, stream>>>(S, n1p);
    }
    sk_fin_k<0><<<256, blk, 0, stream>>>(S, nullptr, n1p, n2p, 0);  // it9 col + exp -> fp32 out
}

// Round 7
// 3081.472 us; speedup vs baseline: 1.2196x; 1.1269x over previous
//
#include <hip/hip_runtime.h>
#include <cstdint>
#include <cstddef>

typedef __bf16 bf16;
typedef float f32x4 __attribute__((ext_vector_type(4)));
typedef bf16  bf16x8 __attribute__((ext_vector_type(8)));

#define NEGV (-1e30f)

// B=64, N=256, IN=1024, HID=OUT=2048
enum { EPI_STORE = 0, EPI_ADD = 1, EPI_BIAS_RELU = 2, EPI_BIAS = 3,
       EPI_STORE_T = 5, EPI_BIAS_RELU_SCALE_T = 6, EPI_PART = 7, EPI_PARTP = 8 };

__device__ __forceinline__ void gload16(const void* g, void* l) {
    __builtin_amdgcn_global_load_lds((const __attribute__((address_space(1))) void*)g,
                                     (__attribute__((address_space(3))) void*)l, 16, 0, 0);
}

// bf16 MFMA GEMM: C[bz] = epi(A[bz] @ B[bz]^T-layout)
// A: [M][K] bf16 row-major.  B: NT layout [N][K] bf16 row-major.
// BK=64; LDS tile [rows][64] with slot-XOR swizzle (slot ^= row&7, 16B slots):
//   staged via global_load_lds (linear LDS dest, inverse-swizzled global src),
//   read via swizzled ds_read_b128 -> 2-way banks (free).  [rule21/m173]
// Tile: 128 x (NTJ*32).  NTJ=4 -> 128x128; NTJ=2 -> 128x64 (4 waves).
// z-batching: ptr += bz * s{A,B,C}.
// EPI_PART: 8 K-slices over two partial-sum A buffers (halves at stride sH):
//   bz = batch*8 + ks; h = ks>>2 selects A-half, kk = ks&3 selects K/4 range;
//   output slice C + (ks*nbatch + batch)*sC  (nbatch = gridDim.z/8).
// EPI_PARTP: split-K=2 producer; bz selects K-half; C += bz*sC (partial sums).
template<int EPI, typename CT, int NTJ>
__global__ __launch_bounds__(256, 2)
void hgemm_k(const bf16* __restrict__ Ab, const bf16* __restrict__ Bb,
             CT* __restrict__ Cb, const int M, const int N, const int K,
             const long long sA, const long long sB, const long long sC,
             const long long sH, const float* __restrict__ bias)
{
    __shared__ bf16 Asl[128 * 64];
    __shared__ bf16 Bsl[NTJ * 32 * 64];
    const int bz = (int)blockIdx.z;
    int ba = bz, kbeg = 0, klen = K;
    long long aoff = 0;
    if constexpr (EPI == EPI_PART) {
        ba = bz >> 3;
        const int ks = bz & 7;
        kbeg = (ks & 3) * (K >> 2); klen = K >> 2;
        aoff = (long long)(ks >> 2) * sH;
    }
    if constexpr (EPI == EPI_PARTP) {
        ba = 0; kbeg = bz * (K >> 1); klen = K >> 1;
    }
    const bf16* __restrict__ A = Ab + (long long)ba * sA + aoff;
    const bf16* __restrict__ B = Bb + (long long)ba * sB;
    CT* __restrict__ C;
    if constexpr (EPI == EPI_PART)
        C = Cb + (long long)((bz & 7) * ((int)gridDim.z >> 3) + (bz >> 3)) * sC;
    else
        C = Cb + (long long)bz * sC;

    const int m0 = blockIdx.y * 128, n0 = blockIdx.x * (NTJ * 32);
    const int tid = (int)threadIdx.x;
    const int lane = tid & 63, wave = tid >> 6;
    const int wm = (wave & 1) * 64, wn = (wave >> 1) * (NTJ * 16);
    const int lrow = lane & 15, quad = lane >> 4;
    const int rb7 = lrow & 7;

    f32x4 acc[4][NTJ];
    const f32x4 zero = {0.f, 0.f, 0.f, 0.f};
#pragma unroll
    for (int i = 0; i < 4; ++i)
#pragma unroll
        for (int j = 0; j < NTJ; ++j) acc[i][j] = zero;

    // staging: round r covers tile rows [r*32, r*32+32); thread t -> LDS off t*16B
    // global col slot inverse-swizzled: g = (t&7) ^ (row&7)
    const int srow = tid >> 3, slot = tid & 7;
    const int gsl = (slot ^ (srow & 7)) * 8;
    const bf16* gA[4]; bf16* lA[4];
#pragma unroll
    for (int r = 0; r < 4; ++r) {
        gA[r] = A + (long long)(m0 + r * 32 + srow) * K + kbeg + gsl;
        lA[r] = Asl + r * 2048 + tid * 8;
    }
    const bf16* gB[NTJ]; bf16* lB[NTJ];
#pragma unroll
    for (int r = 0; r < NTJ; ++r) {
        gB[r] = B + (long long)(n0 + r * 32 + srow) * K + kbeg + gsl;
        lB[r] = Bsl + r * 2048 + tid * 8;
    }

    for (int k0 = 0; k0 < klen; k0 += 64) {
#pragma unroll
        for (int r = 0; r < 4; ++r) { gload16(gA[r], lA[r]); gA[r] += 64; }
#pragma unroll
        for (int r = 0; r < NTJ; ++r) { gload16(gB[r], lB[r]); gB[r] += 64; }
        __syncthreads();
#pragma unroll
        for (int ks = 0; ks < 2; ++ks) {
            const int sl = (((ks << 2) | quad) ^ rb7) * 8;
            bf16x8 af[4], bfr[NTJ];
#pragma unroll
            for (int i = 0; i < 4; ++i)
                af[i] = *(const bf16x8*)(Asl + (size_t)(wm + i * 16 + lrow) * 64 + sl);
#pragma unroll
            for (int j = 0; j < NTJ; ++j)
                bfr[j] = *(const bf16x8*)(Bsl + (size_t)(wn + j * 16 + lrow) * 64 + sl);
#pragma unroll
            for (int i = 0; i < 4; ++i)
#pragma unroll
                for (int j = 0; j < NTJ; ++j)
                    acc[i][j] = __builtin_amdgcn_mfma_f32_16x16x32_bf16(af[i], bfr[j], acc[i][j], 0, 0, 0);
        }
        __syncthreads();
    }

    // C/D layout: col = lane&15, row = quad*4 + reg   [m89-verified]
#pragma unroll
    for (int ti = 0; ti < 4; ++ti) {
        const int gm0 = m0 + wm + ti * 16 + quad * 4;
#pragma unroll
        for (int r = 0; r < 4; ++r) {
            const int gm = gm0 + r;
#pragma unroll
            for (int tj = 0; tj < NTJ; ++tj) {
                const int gn = n0 + wn + tj * 16 + lrow;
                const float v = acc[ti][tj][r];
                CT* cp = C + (size_t)gm * N + gn;
                if constexpr (EPI == EPI_STORE)          *cp = (CT)v;
                else if constexpr (EPI == EPI_PART)      *cp = (CT)v;
                else if constexpr (EPI == EPI_PARTP)     *cp = (CT)v;
                else if constexpr (EPI == EPI_ADD)       *cp = (CT)((float)*cp + v);
                else if constexpr (EPI == EPI_BIAS_RELU) *cp = (CT)fmaxf(v + bias[gn], 0.f);
                else if constexpr (EPI == EPI_BIAS)      *cp = (CT)(v + bias[gn]);
            }
        }
    }
}

// Paired-output GEMM: two N=2048 GEMMs sharing the A operand, fused via z.
// z in [0,4): g = z&1 (graph), w = z>>1 (which B/epilogue).
//   w=0: B=B0, epilogue EPI0 (T-type) -> C0 + g*sC0
//   w=1: B=B1, epilogue EPI1 (row-major) -> C1 + g*sC1
// A = Ab + sel*sA, sel = (w==0 && SWAPA0) ? g^1 : g.
// Same BK=64 + slot-swizzle engine as hgemm_k.
// T-epilogue writes per-256-row-batch transposed: C[b][n][m] (b = gm>>8).
template<int EPI0, int EPI1, bool SWAPA0>
__global__ __launch_bounds__(256, 2)
void hgemm2_k(const bf16* __restrict__ Ab,
              const bf16* __restrict__ B0b, const bf16* __restrict__ B1b,
              bf16* __restrict__ C0b, bf16* __restrict__ C1b,
              const int M, const int N, const int K,
              const long long sA, const long long sC0, const long long sC1,
              const long long sR,
              const float* __restrict__ bias0, const float* __restrict__ bias1,
              const float* __restrict__ rowscale)
{
    __shared__ bf16 Asl[128 * 64];
    __shared__ bf16 Bsl[128 * 64];
    const int bz = (int)blockIdx.z;
    const int g = bz & 1, wsel = bz >> 1;
    const int asel = (wsel == 0 && SWAPA0) ? (g ^ 1) : g;
    const bf16* __restrict__ A = Ab + (long long)asel * sA;
    const bf16* __restrict__ B = wsel ? B1b : B0b;
    bf16* __restrict__ C = wsel ? (C1b + (long long)g * sC1)
                                : (C0b + (long long)g * sC0);
    const float* __restrict__ bias = wsel ? bias1 : bias0;
    const float* __restrict__ rs = rowscale + (long long)g * sR;

    const int m0 = blockIdx.y * 128, n0 = blockIdx.x * 128;
    const int tid = (int)threadIdx.x;
    const int lane = tid & 63, wave = tid >> 6;
    const int wm = (wave & 1) * 64, wn = (wave >> 1) * 64;
    const int lrow = lane & 15, quad = lane >> 4;
    const int rb7 = lrow & 7;

    f32x4 acc[4][4];
    const f32x4 zero = {0.f, 0.f, 0.f, 0.f};
#pragma unroll
    for (int i = 0; i < 4; ++i)
#pragma unroll
        for (int j = 0; j < 4; ++j) acc[i][j] = zero;

    const int srow = tid >> 3, slot = tid & 7;
    const int gsl = (slot ^ (srow & 7)) * 8;
    const bf16* gA[4]; bf16* lA[4];
    const bf16* gB[4]; bf16* lB[4];
#pragma unroll
    for (int r = 0; r < 4; ++r) {
        gA[r] = A + (long long)(m0 + r * 32 + srow) * K + gsl;
        lA[r] = Asl + r * 2048 + tid * 8;
        gB[r] = B + (long long)(n0 + r * 32 + srow) * K + gsl;
        lB[r] = Bsl + r * 2048 + tid * 8;
    }

    for (int k0 = 0; k0 < K; k0 += 64) {
#pragma unroll
        for (int r = 0; r < 4; ++r) {
            gload16(gA[r], lA[r]); gA[r] += 64;
            gload16(gB[r], lB[r]); gB[r] += 64;
        }
        __syncthreads();
#pragma unroll
        for (int ks = 0; ks < 2; ++ks) {
            const int sl = (((ks << 2) | quad) ^ rb7) * 8;
            bf16x8 af[4], bfr[4];
#pragma unroll
            for (int i = 0; i < 4; ++i) {
                af[i]  = *(const bf16x8*)(Asl + (size_t)(wm + i * 16 + lrow) * 64 + sl);
                bfr[i] = *(const bf16x8*)(Bsl + (size_t)(wn + i * 16 + lrow) * 64 + sl);
            }
#pragma unroll
            for (int i = 0; i < 4; ++i)
#pragma unroll
                for (int j = 0; j < 4; ++j)
                    acc[i][j] = __builtin_amdgcn_mfma_f32_16x16x32_bf16(af[i], bfr[j], acc[i][j], 0, 0, 0);
        }
        __syncthreads();
    }

    if (wsel == 0) {
        // T-epilogue: per-256-row-batch transposed, packed 4x bf16 along m
#pragma unroll
        for (int ti = 0; ti < 4; ++ti) {
            const int gm0 = m0 + wm + ti * 16 + quad * 4;
#pragma unroll
            for (int tj = 0; tj < 4; ++tj) {
                const int gn = n0 + wn + tj * 16 + lrow;
                union { bf16 h[4]; uint2 u; } p;
#pragma unroll
                for (int r = 0; r < 4; ++r) {
                    float v = acc[ti][tj][r];
                    if constexpr (EPI0 == EPI_BIAS_RELU_SCALE_T)
                        v = fmaxf(v + bias[gn], 0.f) * rs[gm0 + r];
                    p.h[r] = (bf16)v;
                }
                *(uint2*)(C + ((size_t)(gm0 >> 8)) * 524288 +
                          (size_t)gn * 256 + (gm0 & 255)) = p.u;
            }
        }
    } else {
#pragma unroll
        for (int ti = 0; ti < 4; ++ti) {
            const int gm0 = m0 + wm + ti * 16 + quad * 4;
#pragma unroll
            for (int r = 0; r < 4; ++r) {
                const int gm = gm0 + r;
#pragma unroll
                for (int tj = 0; tj < 4; ++tj) {
                    const int gn = n0 + wn + tj * 16 + lrow;
                    const float v = acc[ti][tj][r];
                    bf16* cp = C + (size_t)gm * N + gn;
                    if constexpr (EPI1 == EPI_BIAS_RELU) *cp = (bf16)fmaxf(v + bias[gn], 0.f);
                    else                                 *cp = (bf16)(v + bias[gn]);
                }
            }
        }
    }
}

// fp32 [K][N] -> bf16 [N][K]  (weight transpose-convert)
__global__ __launch_bounds__(256)
void wtrans_k(const float* __restrict__ W, bf16* __restrict__ Wt, const int K, const int N)
{
    __shared__ float tl[32][33];
    const int k0 = blockIdx.y * 32, n0 = blockIdx.x * 32;
    const int tx = (int)threadIdx.x & 31, ty = (int)threadIdx.x >> 5;
#pragma unroll
    for (int q = 0; q < 4; ++q)
        tl[ty + 8 * q][tx] = W[(size_t)(k0 + ty + 8 * q) * N + n0 + tx];
    __syncthreads();
#pragma unroll
    for (int q = 0; q < 4; ++q)
        Wt[(size_t)(n0 + ty + 8 * q) * K + k0 + tx] = (bf16)tl[tx][ty + 8 * q];
}

// fp32 -> bf16 elementwise (vectorized)
__global__ __launch_bounds__(256)
void cvt_k(const float4* __restrict__ in, uint2* __restrict__ out, const long long n4)
{
    long long i = (long long)blockIdx.x * 256 + threadIdx.x;
    const long long st = (long long)gridDim.x * 256;
    for (; i < n4; i += st) {
        const float4 v = in[i];
        union { bf16 h[4]; uint2 u; } p;
        p.h[0] = (bf16)v.x; p.h[1] = (bf16)v.y; p.h[2] = (bf16)v.z; p.h[3] = (bf16)v.w;
        out[i] = p.u;
    }
}

// rcs_cg[((b>>nbl2)*2+g)*nb + (b&(nb-1))][j] = 1 / max(sum_i |A[b,i,j]|, 1e-12)
__global__ __launch_bounds__(256)
void colsum_rcp_k(const float* __restrict__ A, float* __restrict__ rcs,
                  const int nbl2, const int g)
{
    const int b = blockIdx.x, j = (int)threadIdx.x;
    const int cch = b >> nbl2, ii = b & ((1 << nbl2) - 1), nb = 1 << nbl2;
    const float* p = A + (size_t)b * 65536;
    float s = 0.f;
    for (int i = 0; i < 256; ++i) s += fabsf(p[i * 256 + j]);
    rcs[(size_t)((cch * 2 + g) * nb + ii) * 256 + j] = 1.f / fmaxf(s, 1e-12f);
}

// online logsumexp partial merge: (m,s) x (m,s) -> (m,s)
__device__ __forceinline__ float2 lse_comb(float2 x, float2 y) {
    const float M = fmaxf(x.x, y.x);
    float2 r; r.x = M; r.y = x.y * expf(x.x - M) + y.y * expf(y.x - M);
    return r;
}

// Fused mask/tau/Spart-reduce + FIRST row-LSE pass (sinkhorn it=0).
// One chunk (nb batches): grid nb*64 blocks x 256 thr, one 64-lane wave per row.
__global__ __launch_bounds__(256)
void sk_mrow_k(const float* __restrict__ Sp, float* __restrict__ S,
               const int* __restrict__ n1p, const int* __restrict__ n2p,
               const int* __restrict__ taup, const int nb)
{
    const int w = (int)threadIdx.x >> 6, lane = (int)threadIdx.x & 63;
    const int rowg = blockIdx.x * 4 + w;          // [0, nb*256)
    const int b = rowg >> 8, i = rowg & 255;
    const int n1 = n1p[b], n2 = n2p[b];
    const float tau = (float)taup[0];
    const size_t stride = (size_t)nb << 16;
    const size_t base = (size_t)rowg * 256 + (size_t)lane * 4;
    float4 s4 = {0.f, 0.f, 0.f, 0.f};
#pragma unroll
    for (int ks = 0; ks < 8; ++ks) {
        const float4 t = *(const float4*)(Sp + ks * stride + base);
        s4.x += t.x; s4.y += t.y; s4.z += t.z; s4.w += t.w;
    }
    const int j0 = lane * 4;
    float4 v;
    v.x = (i < n1 && j0 + 0 < n2) ? s4.x / tau : NEGV;
    v.y = (i < n1 && j0 + 1 < n2) ? s4.y / tau : NEGV;
    v.z = (i < n1 && j0 + 2 < n2) ? s4.z / tau : NEGV;
    v.w = (i < n1 && j0 + 3 < n2) ? s4.w / tau : NEGV;
    float m = fmaxf(fmaxf(v.x, v.y), fmaxf(v.z, v.w));
#pragma unroll
    for (int off = 32; off > 0; off >>= 1) m = fmaxf(m, __shfl_down(m, off));
    m = __shfl(m, 0);
    float s = expf(v.x - m) + expf(v.y - m) + expf(v.z - m) + expf(v.w - m);
#pragma unroll
    for (int off = 32; off > 0; off >>= 1) s += __shfl_down(s, off);
    s = __shfl(s, 0);
    const float lse = m + logf(s);
    if (i < n1) { v.x -= lse; v.y -= lse; v.z -= lse; v.w -= lse; }
    *(float4*)(S + base) = v;
}

// Row logsumexp pass: one 64-lane wave per row (full S: 4096 blocks).
__global__ __launch_bounds__(256)
void sk_row_k(float* __restrict__ S, const int* __restrict__ n1p)
{
    const int w = (int)threadIdx.x >> 6, lane = (int)threadIdx.x & 63;
    const int rowg = blockIdx.x * 4 + w;
    const int b = rowg >> 8, i = rowg & 255;
    float* p = S + (size_t)rowg * 256;
    float4 v = ((const float4*)p)[lane];
    float m = fmaxf(fmaxf(v.x, v.y), fmaxf(v.z, v.w));
#pragma unroll
    for (int off = 32; off > 0; off >>= 1) m = fmaxf(m, __shfl_down(m, off));
    m = __shfl(m, 0);
    float s = expf(v.x - m) + expf(v.y - m) + expf(v.z - m) + expf(v.w - m);
#pragma unroll
    for (int off = 32; off > 0; off >>= 1) s += __shfl_down(s, off);
    s = __shfl(s, 0);
    const float lse = m + logf(s);
    if (i < n1p[b]) {
        v.x -= lse; v.y -= lse; v.z -= lse; v.w -= lse;
        ((float4*)p)[lane] = v;
    }
}

// Column logsumexp pass: 256 blocks (64 batches x 4 col-chunks) x 256 thr.
// Thread t: column j = chunk*64 + (t&63); rows (t>>6)*64 .. +63 in registers
// (statically indexed v[64]); LDS (m,s) combine across 4 row-chunks.
__global__ __launch_bounds__(256)
void sk_col2_k(float* __restrict__ S, const int* __restrict__ n2p)
{
    __shared__ float2 part[4][64];
    __shared__ float lsev[64];
    const int bid = (int)blockIdx.x;
    const int b = bid >> 2, c0 = (bid & 3) * 64;
    const int t = (int)threadIdx.x, j = c0 + (t & 63), q = t >> 6;
    float* base = S + ((size_t)b << 16) + (size_t)q * 16384 + j;
    float v[64];
#pragma unroll
    for (int i = 0; i < 64; ++i) v[i] = base[i * 256];
    float m = v[0];
#pragma unroll
    for (int i = 1; i < 64; ++i) m = fmaxf(m, v[i]);
    float s = 0.f;
#pragma unroll
    for (int i = 0; i < 64; ++i) s += expf(v[i] - m);
    part[q][t & 63] = make_float2(m, s);
    __syncthreads();
    if (t < 64) {
        float2 a = part[0][t];
        a = lse_comb(a, part[1][t]);
        a = lse_comb(a, part[2][t]);
        a = lse_comb(a, part[3][t]);
        lsev[t] = a.x + logf(a.y);
    }
    __syncthreads();
    if (j < n2p[b]) {
        const float l = lsev[t & 63];
#pragma unroll
        for (int i = 0; i < 64; ++i) base[i * 256] = v[i] - l;
    }
}

// Final col pass (it=9) fused with exp+mask and output writes.
// WRITE_SB=1: bf16 S + S^T chunk-graph-major (replaces sconv), S fp32 untouched.
// WRITE_SB=0: final fp32 S (output).
template<int WRITE_SB>
__global__ __launch_bounds__(256)
void sk_fin_k(float* __restrict__ S, bf16* __restrict__ S2b,
              const int* __restrict__ n1p, const int* __restrict__ n2p,
              const int nbl2)
{
    __shared__ float2 part[4][64];
    __shared__ float lsev[64];
    const int bid = (int)blockIdx.x;
    const int b = bid >> 2, c0 = (bid & 3) * 64;
    const int t = (int)threadIdx.x, j = c0 + (t & 63), q = t >> 6;
    float* base = S + ((size_t)b << 16) + (size_t)q * 16384 + j;
    float v[64];
#pragma unroll
    for (int i = 0; i < 64; ++i) v[i] = base[i * 256];
    float m = v[0];
#pragma unroll
    for (int i = 1; i < 64; ++i) m = fmaxf(m, v[i]);
    float s = 0.f;
#pragma unroll
    for (int i = 0; i < 64; ++i) s += expf(v[i] - m);
    part[q][t & 63] = make_float2(m, s);
    __syncthreads();
    if (t < 64) {
        float2 a = part[0][t];
        a = lse_comb(a, part[1][t]);
        a = lse_comb(a, part[2][t]);
        a = lse_comb(a, part[3][t]);
        lsev[t] = a.x + logf(a.y);
    }
    __syncthreads();
    const int n1 = n1p[b];
    const bool jv = j < n2p[b];
    const float l = jv ? lsev[t & 63] : 0.f;
#pragma unroll
    for (int i = 0; i < 64; ++i) {
        const int row = q * 64 + i;
        v[i] = (row < n1 && jv) ? expf(v[i] - l) : 0.f;
    }
    if constexpr (WRITE_SB) {
        const int nb = 1 << nbl2;
        const int cch = b >> nbl2, ii = b & (nb - 1);
        bf16* sbB = S2b + ((size_t)((cch * 2) * nb + ii) << 16);
        bf16* stB = S2b + ((size_t)((cch * 2 + 1) * nb + ii) << 16);
#pragma unroll
        for (int i = 0; i < 64; ++i)
            sbB[(size_t)(q * 64 + i) * 256 + j] = (bf16)v[i];
#pragma unroll
        for (int w8 = 0; w8 < 8; ++w8) {
            union { bf16 h[8]; uint4 uu; } pk;
#pragma unroll
            for (int e = 0; e < 8; ++e) pk.h[e] = (bf16)v[w8 * 8 + e];
            *(uint4*)(stB + (size_t)j * 256 + q * 64 + w8 * 8) = pk.uu;
        }
    } else {
#pragma unroll
        for (int i = 0; i < 64; ++i) base[i * 256] = v[i];
    }
}

extern "C" void kernel_launch(void* const* d_in, const int* in_sizes, int n_in,
                              void* d_out, int out_size, void* d_ws, size_t ws_size,
                              hipStream_t stream)
{
    (void)in_sizes; (void)n_in; (void)out_size;
    const float* feat1  = (const float*)d_in[0];
    const float* feat2  = (const float*)d_in[1];
    const float* A1     = (const float*)d_in[2];
    const float* A2     = (const float*)d_in[3];
    const float* g0_aW  = (const float*)d_in[4];
    const float* g0_ab  = (const float*)d_in[5];
    const float* g0_uW  = (const float*)d_in[6];
    const float* g0_ub  = (const float*)d_in[7];
    const float* g1_aW  = (const float*)d_in[8];
    const float* g1_ab  = (const float*)d_in[9];
    const float* g1_uW  = (const float*)d_in[10];
    const float* g1_ub  = (const float*)d_in[11];
    const float* aff0_W = (const float*)d_in[12];
    const float* aff1_W = (const float*)d_in[13];
    const float* cross_W = (const float*)d_in[14];
    const float* cross_b = (const float*)d_in[15];
    const int* n1p = (const int*)d_in[16];
    const int* n2p = (const int*)d_in[17];
    const int* taup = (const int*)d_in[20];

    float* S = (float*)d_out;                     // [64,256,256] fp32

    // ---- workspace layout (base = 226,623,488 B) ----
    bf16* w = (bf16*)d_ws;
    bf16* E12b = w;   w += 67108864;              // [nc][2][nb*256][2048]
    bf16* g0aWt = w;  w += 2097152;               // [2048][1024]
    bf16* g0uWt = w;  w += 2097152;
    bf16* g1aWt = w;  w += 4194304;               // [2048][2048]
    bf16* g1uWt = w;  w += 4194304;
    bf16* aff0Wt = w; w += 4194304;
    bf16* aff1Wt = w; w += 4194304;
    bf16* cWtT = w;   w += 4194304;               // cross_W rows 0..2047, transposed
    bf16* cWbT = w;   w += 4194304;               // cross_W rows 2048..4095, transposed
    bf16* A12b = w;   w += 8388608;               // [nc][2][nb][256][256]
    bf16* S2b = w;    w += 8388608;               // [nc][2][nb][256][256] (S then S^T)
    float* rcs_cg = (float*)w; w += 65536;        // [nc][2][nb][256] fp32

    // chunk scratch: Ha (2*nb*1MB) + region2 (max of Fbc2 / H12 / Spart)
    int nb = 1;
    {
        const long long avail = (long long)ws_size - 226623488LL;
        while (nb < 32 && (long long)(nb * 2) * 4194304LL <= avail) nb <<= 1;
    }
    const int nbl2 = __builtin_ctz(nb);
    const int nc = 64 / nb;
    bf16* Ha = w;                                 // [2][nb][2048][256]-T / P0,P1 halves
    bf16* region2 = Ha + (size_t)2 * nb * 524288;
    bf16* Fbc2 = region2;                         // [2][nb*256][1024]   (layer-0 only)
    bf16* H12 = region2;                          // [2][nb*256][2048]   (cross only)
    float* Spart = (float*)region2;               // [8][nb][256][256]   (affinity only)

    const dim3 blk(256);
    const dim3 gF2(16, nb * 2, 4);    // pair-fused row GEMM, N=2048, 128x128 tile
    const dim3 gAdd(16, 2, nb * 2);   // batched adjacency/S ADD
    const dim3 gP(32, nb * 2, 2);     // P GEMM split-K=2, 128x64 tile
    const dim3 gPart(4, 2, nb * 8);   // 8-slice affinity inner product, 128x64 tile

    const long long EC = (long long)nb * 524288;  // per-graph chunk stride (bf16 elems)
    const long long FC = (long long)nb * 262144;  // per-graph feat chunk stride
    const long long PH = (long long)nb * 524288;  // P-half stride (elems)

    // ---- prep
    wtrans_k<<<dim3(64, 32), blk, 0, stream>>>(g0_aW, g0aWt, 1024, 2048);
    wtrans_k<<<dim3(64, 32), blk, 0, stream>>>(g0_uW, g0uWt, 1024, 2048);
    wtrans_k<<<dim3(64, 64), blk, 0, stream>>>(g1_aW, g1aWt, 2048, 2048);
    wtrans_k<<<dim3(64, 64), blk, 0, stream>>>(g1_uW, g1uWt, 2048, 2048);
    wtrans_k<<<dim3(64, 64), blk, 0, stream>>>(aff0_W, aff0Wt, 2048, 2048);
    wtrans_k<<<dim3(64, 64), blk, 0, stream>>>(aff1_W, aff1Wt, 2048, 2048);
    wtrans_k<<<dim3(64, 64), blk, 0, stream>>>(cross_W, cWtT, 2048, 2048);
    wtrans_k<<<dim3(64, 64), blk, 0, stream>>>(cross_W + 4194304, cWbT, 2048, 2048);
    for (int c = 0; c < nc; ++c) {
        cvt_k<<<256, blk, 0, stream>>>((const float4*)(A1 + (long long)c * nb * 65536),
                                       (uint2*)(A12b + (long long)c * 2 * nb * 65536),
                                       (long long)nb * 16384);
        cvt_k<<<256, blk, 0, stream>>>((const float4*)(A2 + (long long)c * nb * 65536),
                                       (uint2*)(A12b + (long long)(c * 2 + 1) * nb * 65536),
                                       (long long)nb * 16384);
    }
    colsum_rcp_k<<<64, blk, 0, stream>>>(A1, rcs_cg, nbl2, 0);
    colsum_rcp_k<<<64, blk, 0, stream>>>(A2, rcs_cg, nbl2, 1);

    // ---- layer 0 Gconv + affinity 0 (chunked; graphs AND aW/uW fused via blockIdx.z)
    for (int c = 0; c < nc; ++c) {
        bf16* E12c = E12b + (long long)c * 2 * EC;
        const float* rsc = rcs_cg + (long long)c * 2 * nb * 256;
        cvt_k<<<1024, blk, 0, stream>>>((const float4*)(feat1 + (long long)c * nb * 262144),
                                        (uint2*)Fbc2, (long long)nb * 65536);
        cvt_k<<<1024, blk, 0, stream>>>((const float4*)(feat2 + (long long)c * nb * 262144),
                                        (uint2*)(Fbc2 + FC), (long long)nb * 65536);
        hgemm2_k<EPI_BIAS_RELU_SCALE_T, EPI_BIAS_RELU, false><<<gF2, blk, 0, stream>>>(
            Fbc2, g0aWt, g0uWt, Ha, E12c, nb * 256, 2048, 1024,
            FC, EC, EC, nb * 256, g0_ab, g0_ub, rsc);
        hgemm_k<EPI_ADD, bf16, 4><<<gAdd, blk, 0, stream>>>(               // E += A @ ax
            A12b + (long long)c * 2 * nb * 65536, Ha, E12c, 256, 2048, 256,
            65536, 524288, 524288, 0, nullptr);
        hgemm_k<EPI_PARTP, bf16, 2><<<gP, blk, 0, stream>>>(               // P0,P1 = E1@aff0W (split-K)
            E12c, aff0Wt, Ha, nb * 256, 2048, 2048, 0, 0, PH, 0, nullptr);
        hgemm_k<EPI_PART, float, 2><<<gPart, blk, 0, stream>>>(            // Spart = (P0+P1)@E2^T
            Ha, E12c + EC, Spart, 256, 256, 2048, 524288, 524288, 65536, PH, nullptr);
        sk_mrow_k<<<nb * 64, blk, 0, stream>>>(                            // mask/tau + row it0
            Spart, S + (long long)c * nb * 65536, n1p + c * nb, n2p + c * nb, taup, nb);
    }
    for (int p = 0; p < 4; ++p) {                 // it1..it8
        sk_col2_k<<<256, blk, 0, stream>>>(S, n2p);
        sk_row_k<<<4096, blk, 0, stream>>>(S, n1p);
    }
    sk_fin_k<1><<<256, blk, 0, stream>>>(S, S2b, n1p, n2p, nbl2);   // it9 col + exp + S/S^T bf16

    // ---- cross update + layer 1 + affinity 1 (chunked, pair-fused)
    for (int c = 0; c < nc; ++c) {
        bf16* E12c = E12b + (long long)c * 2 * EC;
        const float* rsc = rcs_cg + (long long)c * 2 * nb * 256;
        // Ha[g]=(E_{g^1}@cWb)^T ; H12[g]=E_g@cWt+b   [one dispatch, z=4, SWAPA0]
        hgemm2_k<EPI_STORE_T, EPI_BIAS, true><<<gF2, blk, 0, stream>>>(
            E12c, cWbT, cWtT, Ha, H12, nb * 256, 2048, 2048,
            EC, EC, EC, 0, nullptr, cross_b, nullptr);
        // H12[0] += S@Ha[0], H12[1] += S^T@Ha[1]
        hgemm_k<EPI_ADD, bf16, 4><<<gAdd, blk, 0, stream>>>(
            S2b + (long long)c * 2 * nb * 65536, Ha, H12, 256, 2048, 256,
            65536, 524288, 524288, 0, nullptr);
        // layer 1: Ha = (rcs*relu(H12@aW+b))^T ; E = relu(H12@uW+b)
        hgemm2_k<EPI_BIAS_RELU_SCALE_T, EPI_BIAS_RELU, false><<<gF2, blk, 0, stream>>>(
            H12, g1aWt, g1uWt, Ha, E12c, nb * 256, 2048, 2048,
            EC, EC, EC, nb * 256, g1_ab, g1_ub, rsc);
        hgemm_k<EPI_ADD, bf16, 4><<<gAdd, blk, 0, stream>>>(
            A12b + (long long)c * 2 * nb * 65536, Ha, E12c, 256, 2048, 256,
            65536, 524288, 524288, 0, nullptr);
        // affinity 1
        hgemm_k<EPI_PARTP, bf16, 2><<<gP, blk, 0, stream>>>(
            E12c, aff1Wt, Ha, nb * 256, 2048, 2048, 0, 0, PH, 0, nullptr);
        hgemm_k<EPI_PART, float, 2><<<gPart, blk, 0, stream>>>(
            Ha, E12c + EC, Spart, 256, 256, 2048, 524288, 524288, 65536, PH, nullptr);
        sk_mrow_k<<<nb * 64, blk, 0, stream>>>(
            Spart, S + (long long)c * nb * 65536, n1p + c * nb, n2p + c * nb, taup, nb);
    }
    for (int p = 0; p < 4; ++p) {
        sk_col2_k<<<256, blk, 0, stream>>>(S, n2p);
        sk_row_k<<<4096, blk, 0, stream>>>(S, n1p);
    }
    sk_fin_k<0><<<256, blk, 0, stream>>>(S, nullptr, n1p, n2p, 0);  // it9 col + exp -> fp32 out
}